// Round 6
// baseline (403.394 us; speedup 1.0000x reference)
//
#include <hip/hip_runtime.h>
#include <hip/hip_bf16.h>

#define N_NODES    50000
#define DIM        128
#define NUM_GRAPHS 64
#define NUM_CLASSES 3
#define NPAD       50176   // 196*256
#define XPITCH     136     // LDS row pitch in ushorts (17 x 16B, odd -> conflict-free b128)
#define PSTRIDE    (NPAD * 16)   // uints per channel-panel

typedef unsigned short ushort_t;
typedef unsigned int   uint_t;
typedef __attribute__((ext_vector_type(8))) short short8;
typedef __attribute__((ext_vector_type(4))) float f32x4;

__device__ __forceinline__ ushort_t f2bf(float f) {
    union { float f; uint_t u; } v; v.f = f;
    uint_t r = v.u + 0x7fffu + ((v.u >> 16) & 1u);   // RNE
    return (ushort_t)(r >> 16);
}
__device__ __forceinline__ float bflo(uint_t u) {
    union { uint_t u; float f; } v; v.u = u << 16; return v.f;
}
__device__ __forceinline__ float bfhi(uint_t u) {
    union { uint_t u; float f; } v; v.u = u & 0xffff0000u; return v.f;
}

// Panel gather: subgroup e = lane>>4 handles edge p+e / p+4+e; lane c = lane&15
// holds channels {pan*32+2c, +1} (one uint per row-load, 4 rows per inst = same
// inst count/edge as the proven round-0 core). 8-edge double-buffered pipeline.
// Returns the FULL per-node sum (cross-subgroup reduced) incl. the self row.
__device__ __forceinline__ float2 panel_gather(
    int n, int e, int c, const int* __restrict__ rowptr,
    const int* __restrict__ csr_src, const uint_t* __restrict__ Tp)
{
    float ax = 0.f, ay = 0.f;
    int p0 = rowptr[n], p1 = rowptr[n + 1];
    int p = p0;
    int nb = (p1 - p0) >> 3;
    if (nb > 0) {
        int s0 = csr_src[p + e], s1 = csr_src[p + 4 + e];
        uint_t u0 = Tp[s0 * 16 + c], u1 = Tp[s1 * 16 + c];
        for (int b = 1; b < nb; ++b) {
            int t0 = csr_src[p + 8 + e], t1 = csr_src[p + 12 + e];
            uint_t v0 = Tp[t0 * 16 + c], v1 = Tp[t1 * 16 + c];
            ax += bflo(u0) + bflo(u1);
            ay += bfhi(u0) + bfhi(u1);
            u0 = v0; u1 = v1; p += 8;
        }
        ax += bflo(u0) + bflo(u1);
        ay += bfhi(u0) + bfhi(u1);
        p += 8;
    }
    int cnt = p1 - p;                       // 0..7 tail
    if (cnt > 0) {
        uint_t u0 = 0, u1 = 0;
        if (e < cnt)     { int s = csr_src[p + e];     u0 = Tp[s * 16 + c]; }
        if (4 + e < cnt) { int s = csr_src[p + 4 + e]; u1 = Tp[s * 16 + c]; }
        ax += bflo(u0) + bflo(u1);
        ay += bfhi(u0) + bfhi(u1);
    }
    ax += __shfl_xor(ax, 16); ax += __shfl_xor(ax, 32);
    ay += __shfl_xor(ay, 16); ay += __shfl_xor(ay, 32);
    uint_t us = Tp[n * 16 + c];             // self loop, counted once
    return make_float2(ax + bflo(us), ay + bfhi(us));
}

// ---------------- init ----------------
__global__ void k_init(int* degi, float* pooled, float* counts) {
    int i = blockIdx.x * 256 + threadIdx.x;
    if (i < NPAD) degi[i] = 0;
    if (i < NUM_GRAPHS * DIM) pooled[i] = 0.0f;
    if (i < NUM_GRAPHS) counts[i] = 0.0f;
}

// ---------------- W -> Wt bf16 transpose (all 3 layers) ----------------
__global__ void k_prep(const float* __restrict__ W1, const float* __restrict__ W2,
                       const float* __restrict__ W3, ushort_t* __restrict__ Wt) {
    int i = blockIdx.x * 256 + threadIdx.x;
    int mat = i >> 14;
    int idx = i & 16383;
    const float* W = (mat == 0) ? W1 : (mat == 1) ? W2 : W3;
    int n = idx >> 7, k = idx & 127;
    Wt[mat * 16384 + n * 128 + k] = f2bf(W[k * 128 + n]);
}

// ---------------- degree histogram; atomic return = within-row rank ----------------
__global__ void k_count(const int* __restrict__ dst, int* degi, int* rank, int nedges) {
    int e = blockIdx.x * 256 + threadIdx.x;
    if (e < nedges) rank[e] = atomicAdd(&degi[dst[e]], 1);
}

// ---------------- scan ----------------
__global__ __launch_bounds__(256) void k_scan1(const int* __restrict__ degi,
                                               int* rowptr, int* bsum) {
    __shared__ int sh[256];
    int i = blockIdx.x * 256 + threadIdx.x;
    int v = degi[i];
    sh[threadIdx.x] = v;
    __syncthreads();
    for (int off = 1; off < 256; off <<= 1) {
        int t = (threadIdx.x >= off) ? sh[threadIdx.x - off] : 0;
        __syncthreads();
        sh[threadIdx.x] += t;
        __syncthreads();
    }
    rowptr[i] = sh[threadIdx.x] - v;
    if (threadIdx.x == 255) bsum[blockIdx.x] = sh[255];
}

__global__ __launch_bounds__(256) void k_scan2(int* bsum, int nblocks) {
    __shared__ int sh[256];
    int v = (threadIdx.x < nblocks) ? bsum[threadIdx.x] : 0;
    sh[threadIdx.x] = v;
    __syncthreads();
    for (int off = 1; off < 256; off <<= 1) {
        int t = (threadIdx.x >= off) ? sh[threadIdx.x - off] : 0;
        __syncthreads();
        sh[threadIdx.x] += t;
        __syncthreads();
    }
    if (threadIdx.x < nblocks) bsum[threadIdx.x] = sh[threadIdx.x] - v;
}

__global__ __launch_bounds__(256) void k_scan3(int* rowptr, const int* __restrict__ bsum,
                                               const int* __restrict__ degi,
                                               float* dinv) {
    int i = blockIdx.x * 256 + threadIdx.x;
    rowptr[i] = rowptr[i] + bsum[blockIdx.x];
    if (i < N_NODES) dinv[i] = rsqrtf((float)degi[i] + 1.0f);
}

// ---------------- CSR fill: atomic-free scatter via precomputed rank ----------------
__global__ void k_fill(const int* __restrict__ src, const int* __restrict__ dst,
                       const int* __restrict__ rank, const int* __restrict__ rowptr,
                       int* csr_src, int nedges) {
    int e = blockIdx.x * 256 + threadIdx.x;
    if (e < nedges) csr_src[rowptr[dst[e]] + rank[e]] = src[e];
}

// ---------------- layer-1 matmul: TbA' = (x @ W1) * dinv[row], panel layout ----------------
__global__ __launch_bounds__(256) void k_mm1(
    const float* __restrict__ xin, const ushort_t* __restrict__ WtG,
    const float* __restrict__ dinv, ushort_t* __restrict__ TbOut)
{
    __shared__ ushort_t Wl[DIM * XPITCH];
    __shared__ ushort_t Xl[64 * XPITCH];

    const int tid = threadIdx.x;
    const int rowbase = blockIdx.x * 64;

    #pragma unroll
    for (int i = 0; i < 8; ++i) {
        int g = tid + i * 256;
        uint4 v = ((const uint4*)WtG)[g];
        *((uint4*)&Wl[(g >> 4) * XPITCH + (g & 15) * 8]) = v;
    }
    #pragma unroll
    for (int i = 0; i < 8; ++i) {
        int c = tid + i * 256;
        int row = c >> 5;
        int grow = rowbase + row;
        float4 f = make_float4(0.f, 0.f, 0.f, 0.f);
        if (grow < N_NODES)
            f = ((const float4*)xin)[(long long)rowbase * 32 + c];
        ushort4 h;
        h.x = f2bf(f.x); h.y = f2bf(f.y); h.z = f2bf(f.z); h.w = f2bf(f.w);
        *((ushort4*)&Xl[row * XPITCH + (c & 31) * 4]) = h;
    }
    __syncthreads();

    const int wave = tid >> 6;
    const int lane = tid & 63;
    const int quad = lane >> 4;
    const int lm   = lane & 15;
    const int m0   = wave * 16;

    short8 af[4];
    #pragma unroll
    for (int k0 = 0; k0 < 4; ++k0)
        af[k0] = *(const short8*)&Xl[(m0 + lm) * XPITCH + k0 * 32 + quad * 8];

    int noder[4]; float di[4]; bool okr[4];
    #pragma unroll
    for (int r = 0; r < 4; ++r) {
        noder[r] = rowbase + m0 + quad * 4 + r;
        okr[r] = (noder[r] < N_NODES);
        di[r] = okr[r] ? dinv[noder[r]] : 0.f;
    }

    for (int n0 = 0; n0 < DIM; n0 += 16) {
        f32x4 acc = {0.f, 0.f, 0.f, 0.f};
        #pragma unroll
        for (int k0 = 0; k0 < 4; ++k0) {
            short8 bf = *(const short8*)&Wl[(n0 + lm) * XPITCH + k0 * 32 + quad * 8];
            acc = __builtin_amdgcn_mfma_f32_16x16x32_bf16(af[k0], bf, acc, 0, 0, 0);
        }
        int n = n0 + lm;
        int pn = n >> 5;
        #pragma unroll
        for (int r = 0; r < 4; ++r)
            if (okr[r])
                TbOut[(size_t)(pn * NPAD + noder[r]) * 32 + (n & 31)] =
                    f2bf(acc[r] * di[r]);
    }
}

// ---------------- panel gather: X = ReLU(b + dinv[n]*Sum Tb'[s]) -> bf16 panels ----------------
// panel = blockIdx.x & 3 -> with round-robin block->XCD dispatch, XCD pair {p,p+4}
// touches ONLY panel p (3.2 MB < 4 MB L2). 32-node chunks, 8 nodes/wave.
__global__ __launch_bounds__(256) void k_pgather(
    const int* __restrict__ rowptr, const int* __restrict__ csr_src,
    const float* __restrict__ dinv, const uint_t* __restrict__ Tbp,
    const float* __restrict__ b_prev, uint_t* __restrict__ Xg)
{
    const int tid  = threadIdx.x;
    const int wave = tid >> 6;
    const int lane = tid & 63;
    const int e    = lane >> 4;
    const int c    = lane & 15;
    const int pan  = blockIdx.x & 3;
    const int base = (blockIdx.x >> 2) * 32 + wave * 8;

    const uint_t* Tp = Tbp + (size_t)pan * PSTRIDE;
    uint_t*       Xp = Xg  + (size_t)pan * PSTRIDE;
    float2 bb = ((const float2*)b_prev)[pan * 16 + c];

    #pragma unroll 1
    for (int i = 0; i < 8; ++i) {
        int n = base + i;
        float ax = 0.f, ay = 0.f;
        if (n < N_NODES) {
            float2 a = panel_gather(n, e, c, rowptr, csr_src, Tp);
            float dd = dinv[n];
            ax = fmaxf(bb.x + a.x * dd, 0.f);
            ay = fmaxf(bb.y + a.y * dd, 0.f);
        }
        if (e == 0) {
            uint_t hx = f2bf(ax), hy = f2bf(ay);
            __builtin_nontemporal_store((hy << 16) | hx, &Xp[n * 16 + c]);
        }
    }
}

// ---------------- dense MM: Tb' = (X @ W) * dinv, X in bf16 panels ----------------
__global__ __launch_bounds__(256) void k_mm(
    const uint_t* __restrict__ Xg, const ushort_t* __restrict__ WtG,
    const float* __restrict__ dinv, ushort_t* __restrict__ TbOut)
{
    __shared__ ushort_t Wl[DIM * XPITCH];
    __shared__ ushort_t Xl[64 * XPITCH];

    const int tid = threadIdx.x;
    const int rowbase = blockIdx.x * 64;

    #pragma unroll
    for (int i = 0; i < 8; ++i) {
        int g = tid + i * 256;
        uint4 v = ((const uint4*)WtG)[g];
        *((uint4*)&Wl[(g >> 4) * XPITCH + (g & 15) * 8]) = v;
    }
    // X tile: 64 rows x 128 ch bf16 from 4 panels = 1024 uint4
    #pragma unroll
    for (int i = 0; i < 4; ++i) {
        int g = tid + i * 256;
        int r = g >> 4, rem = g & 15, pq = rem >> 2, q = rem & 3;
        uint4 v = ((const uint4*)Xg)[(size_t)(pq * NPAD + rowbase + r) * 4 + q];
        *((uint4*)&Xl[r * XPITCH + pq * 32 + q * 8]) = v;
    }
    __syncthreads();

    const int wave = tid >> 6;
    const int lane = tid & 63;
    const int quad = lane >> 4;
    const int lm   = lane & 15;
    const int m0   = wave * 16;

    short8 af[4];
    #pragma unroll
    for (int k0 = 0; k0 < 4; ++k0)
        af[k0] = *(const short8*)&Xl[(m0 + lm) * XPITCH + k0 * 32 + quad * 8];

    int noder[4]; float di[4]; bool okr[4];
    #pragma unroll
    for (int r = 0; r < 4; ++r) {
        noder[r] = rowbase + m0 + quad * 4 + r;
        okr[r] = (noder[r] < N_NODES);
        di[r] = okr[r] ? dinv[noder[r]] : 0.f;
    }

    for (int n0 = 0; n0 < DIM; n0 += 16) {
        f32x4 acc = {0.f, 0.f, 0.f, 0.f};
        #pragma unroll
        for (int k0 = 0; k0 < 4; ++k0) {
            short8 bf = *(const short8*)&Wl[(n0 + lm) * XPITCH + k0 * 32 + quad * 8];
            acc = __builtin_amdgcn_mfma_f32_16x16x32_bf16(af[k0], bf, acc, 0, 0, 0);
        }
        int n = n0 + lm;
        int pn = n >> 5;
        #pragma unroll
        for (int r = 0; r < 4; ++r)
            if (okr[r])
                TbOut[(size_t)(pn * NPAD + noder[r]) * 32 + (n & 31)] =
                    f2bf(acc[r] * di[r]);
    }
}

// ---------------- panel gather + mean-pool ----------------
// Same panel partition; LDS run-flush accumulation per 32-node chunk; each
// panel block owns 32 columns; counts from panel-0 blocks only.
__global__ __launch_bounds__(256) void k_ppool(
    const int* __restrict__ rowptr, const int* __restrict__ csr_src,
    const float* __restrict__ dinv, const uint_t* __restrict__ Tbp,
    const float* __restrict__ b3, const int* __restrict__ batch,
    float* pooled, float* counts)
{
    __shared__ float lp[8][DIM];
    __shared__ float lc[8];
    __shared__ int   used[8];

    const int tid  = threadIdx.x;
    const int wave = tid >> 6;
    const int lane = tid & 63;
    const int e    = lane >> 4;
    const int c    = lane & 15;
    const int pan  = blockIdx.x & 3;
    const int blk0 = (blockIdx.x >> 2) * 32;

    const uint_t* Tp = Tbp + (size_t)pan * PSTRIDE;
    const int ch = pan * 32 + 2 * c;

    #pragma unroll
    for (int i = 0; i < 4; ++i) ((float*)lp)[tid + i * 256] = 0.f;
    if (tid < 8) { lc[tid] = 0.f; used[tid] = 0; }
    __syncthreads();

    const int gbase = batch[min(blk0, N_NODES - 1)];
    int n0 = blk0 + wave * 8;

    if (n0 < N_NODES) {
        int nend = min(n0 + 8, N_NODES);
        float2 bb = ((const float2*)b3)[pan * 16 + c];
        int cur = batch[n0];
        int runstart = n0;
        float px = 0.f, py = 0.f;

        for (int n = n0; n < nend; ++n) {
            int g = batch[n];
            if (g != cur) {
                int slot = cur - gbase;
                if (slot < 8) {
                    if (e == 0) {
                        atomicAdd(&lp[slot][ch], px);
                        atomicAdd(&lp[slot][ch + 1], py);
                        used[slot] = 1;
                    }
                    if (lane == 0 && pan == 0) atomicAdd(&lc[slot], (float)(n - runstart));
                } else {
                    if (e == 0) {
                        atomicAdd(&pooled[cur * DIM + ch], px);
                        atomicAdd(&pooled[cur * DIM + ch + 1], py);
                    }
                    if (lane == 0 && pan == 0) atomicAdd(&counts[cur], (float)(n - runstart));
                }
                px = 0.f; py = 0.f; cur = g; runstart = n;
            }
            float2 a = panel_gather(n, e, c, rowptr, csr_src, Tp);
            float dd = dinv[n];
            px += bb.x + a.x * dd;
            py += bb.y + a.y * dd;
        }
        int slot = cur - gbase;
        if (slot < 8) {
            if (e == 0) {
                atomicAdd(&lp[slot][ch], px);
                atomicAdd(&lp[slot][ch + 1], py);
                used[slot] = 1;
            }
            if (lane == 0 && pan == 0) atomicAdd(&lc[slot], (float)(nend - runstart));
        } else {
            if (e == 0) {
                atomicAdd(&pooled[cur * DIM + ch], px);
                atomicAdd(&pooled[cur * DIM + ch + 1], py);
            }
            if (lane == 0 && pan == 0) atomicAdd(&counts[cur], (float)(nend - runstart));
        }
    }
    __syncthreads();

    #pragma unroll
    for (int s = 0; s < 8; ++s) {
        if (used[s]) {
            if (tid < 32) atomicAdd(&pooled[(gbase + s) * DIM + pan * 32 + tid],
                                    lp[s][pan * 32 + tid]);
            if (tid == 32 && pan == 0 && lc[s] != 0.f)
                atomicAdd(&counts[gbase + s], lc[s]);
        }
    }
}

// ---------------- classifier head ----------------
__global__ __launch_bounds__(128) void k_cls(
    const float* __restrict__ pooled, const float* __restrict__ counts,
    const float* __restrict__ C1, const float* __restrict__ bc1,
    const float* __restrict__ C2, const float* __restrict__ bc2,
    float* out)
{
    __shared__ float pm[DIM];
    __shared__ float gv[DIM];
    int g = blockIdx.x, j = threadIdx.x;
    float cnt = fmaxf(counts[g], 1.0f);
    pm[j] = pooled[g * DIM + j] / cnt;
    __syncthreads();
    float a = bc1[j];
    for (int k = 0; k < DIM; ++k) a += pm[k] * C1[k * DIM + j];
    gv[j] = fmaxf(a, 0.f);
    __syncthreads();
    if (j < NUM_CLASSES) {
        float o = bc2[j];
        for (int k = 0; k < DIM; ++k) o += gv[k] * C2[k * NUM_CLASSES + j];
        out[g * NUM_CLASSES + j] = o;
    }
}

extern "C" void kernel_launch(void* const* d_in, const int* in_sizes, int n_in,
                              void* d_out, int out_size, void* d_ws, size_t ws_size,
                              hipStream_t stream) {
    const float* x    = (const float*)d_in[0];
    const int*   ei   = (const int*)d_in[1];
    const int*   batch= (const int*)d_in[2];
    const float* W1   = (const float*)d_in[3];
    const float* b1   = (const float*)d_in[4];
    const float* W2   = (const float*)d_in[5];
    const float* b2   = (const float*)d_in[6];
    const float* W3   = (const float*)d_in[7];
    const float* b3   = (const float*)d_in[8];
    const float* C1   = (const float*)d_in[9];
    const float* bc1  = (const float*)d_in[10];
    const float* C2   = (const float*)d_in[11];
    const float* bc2  = (const float*)d_in[12];

    const int nedges = in_sizes[1] / 2;
    const int* src = ei;
    const int* dst = ei + nedges;

    // workspace layout (4-byte units)
    float*    dinv    = (float*)d_ws;                           // NPAD
    uint_t*   TbA     = (uint_t*)(dinv + NPAD);                 // NPAD*64 (4 panels)
    uint_t*   TbB     = TbA + (size_t)NPAD * 64;                // NPAD*64
    uint_t*   Xb      = TbB + (size_t)NPAD * 64;                // NPAD*64
    float*    pooled  = (float*)(Xb + (size_t)NPAD * 64);       // 8192
    float*    counts  = pooled + NUM_GRAPHS * DIM;              // 64
    int*      degi    = (int*)(counts + 64);                    // NPAD
    int*      rowptr  = degi + NPAD;                            // NPAD+256
    int*      bsum    = rowptr + NPAD + 256;                    // 256
    int*      rank    = bsum + 256;                             // nedges
    int*      csr_src = rank + nedges;                          // nedges
    ushort_t* Wt      = (ushort_t*)(csr_src + nedges);          // 3*16384 bf16

    const int nodeBlocks = NPAD / 256;                     // 196
    const int mmBlocks   = (N_NODES + 63) / 64;            // 782
    const int panBlocks  = (NPAD / 32) * 4;                // 6272
    const int edgeBlocks = (nedges + 255) / 256;           // 3125

    k_init<<<nodeBlocks, 256, 0, stream>>>(degi, pooled, counts);
    k_prep<<<192, 256, 0, stream>>>(W1, W2, W3, Wt);
    k_count<<<edgeBlocks, 256, 0, stream>>>(dst, degi, rank, nedges);
    k_scan1<<<nodeBlocks, 256, 0, stream>>>(degi, rowptr, bsum);
    k_scan2<<<1, 256, 0, stream>>>(bsum, nodeBlocks);
    k_scan3<<<nodeBlocks, 256, 0, stream>>>(rowptr, bsum, degi, dinv);
    k_fill<<<edgeBlocks, 256, 0, stream>>>(src, dst, rank, rowptr, csr_src, nedges);

    k_mm1<<<mmBlocks, 256, 0, stream>>>(x, Wt, dinv, (ushort_t*)TbA);

    k_pgather<<<panBlocks, 256, 0, stream>>>(rowptr, csr_src, dinv, TbA, b1, Xb);
    k_mm<<<mmBlocks, 256, 0, stream>>>(Xb, Wt + 16384, dinv, (ushort_t*)TbB);

    k_pgather<<<panBlocks, 256, 0, stream>>>(rowptr, csr_src, dinv, TbB, b2, Xb);
    k_mm<<<mmBlocks, 256, 0, stream>>>(Xb, Wt + 32768, dinv, (ushort_t*)TbA);

    k_ppool<<<panBlocks, 256, 0, stream>>>(rowptr, csr_src, dinv, TbA,
                                           b3, batch, pooled, counts);
    k_cls<<<NUM_GRAPHS, 128, 0, stream>>>(pooled, counts, C1, bc1, C2, bc2,
                                          (float*)d_out);
}

// Round 7
// 295.017 us; speedup vs baseline: 1.3674x; 1.3674x over previous
//
#include <hip/hip_runtime.h>
#include <hip/hip_bf16.h>

#define N_NODES    50000
#define DIM        128
#define NUM_GRAPHS 64
#define NUM_CLASSES 3
#define NPAD       50176   // 196*256
#define XPITCH     136     // LDS row pitch in ushorts (17 x 16B, odd -> conflict-free b128)

typedef unsigned short ushort_t;
typedef unsigned int   uint_t;
typedef __attribute__((ext_vector_type(8))) short short8;
typedef __attribute__((ext_vector_type(4))) float f32x4;

__device__ __forceinline__ ushort_t f2bf(float f) {
    union { float f; uint_t u; } v; v.f = f;
    uint_t r = v.u + 0x7fffu + ((v.u >> 16) & 1u);   // RNE
    return (ushort_t)(r >> 16);
}
__device__ __forceinline__ float bflo(uint_t u) {
    union { uint_t u; float f; } v; v.u = u << 16; return v.f;
}
__device__ __forceinline__ float bfhi(uint_t u) {
    union { uint_t u; float f; } v; v.u = u & 0xffff0000u; return v.f;
}

// readlane-fed gather. Node's indices arrive via ONE coalesced load (myidx0,
// prefetched by caller); row loads take their index from readlane (2-cy VALU
// -> SGPR, NO ds_bpermute as in the failed round-3 shfl version, no idx VMEM
// on the batch critical path, SGPR-base saddr row loads). Row access pattern
// and 8-deep 2-accumulator rotation preserved from the proven round-0 core.
__device__ __forceinline__ void gather_rl(
    int n, int lane, int myidx0, int p0, int p1,
    const int* __restrict__ csr_src, const uint_t* __restrict__ Tb,
    float2& acc)
{
    uint_t us = Tb[n * 64 + lane];      // self loop (issues first)
    float2 a0 = make_float2(bflo(us), bfhi(us));
    float2 a1 = make_float2(0.f, 0.f);
    int deg = p1 - p0;
    if (deg < 0) deg = 0;
    int nchunk = (deg + 63) >> 6;       // bounded; >64-degree is rare
    int myidx = myidx0;
    for (int ck = 0; ck < nchunk; ++ck) {
        int base = p0 + (ck << 6);
        int cnt = p1 - base; if (cnt > 64) cnt = 64;
        int nb = cnt >> 3;
        if (nb > 0) {
            uint_t ucur[8];
            #pragma unroll
            for (int q = 0; q < 8; ++q)
                ucur[q] = Tb[__builtin_amdgcn_readlane(myidx, q) * 64 + lane];
            for (int b = 1; b < nb; ++b) {
                int jb = b * 8;
                uint_t unxt[8];
                #pragma unroll
                for (int q = 0; q < 8; ++q)
                    unxt[q] = Tb[__builtin_amdgcn_readlane(myidx, jb + q) * 64 + lane];
                #pragma unroll
                for (int q = 0; q < 8; q += 2) {
                    a0.x += bflo(ucur[q]);     a0.y += bfhi(ucur[q]);
                    a1.x += bflo(ucur[q + 1]); a1.y += bfhi(ucur[q + 1]);
                }
                #pragma unroll
                for (int q = 0; q < 8; ++q) ucur[q] = unxt[q];
            }
            #pragma unroll
            for (int q = 0; q < 8; q += 2) {
                a0.x += bflo(ucur[q]);     a0.y += bfhi(ucur[q]);
                a1.x += bflo(ucur[q + 1]); a1.y += bfhi(ucur[q + 1]);
            }
        }
        for (int j = nb * 8; j < cnt; ++j) {     // uniform scalar tail loop
            uint_t u = Tb[__builtin_amdgcn_readlane(myidx, j) * 64 + lane];
            a0.x += bflo(u); a0.y += bfhi(u);
        }
        if (ck + 1 < nchunk) {                   // rare: degree > 64
            int c2 = p1 - (base + 64);
            myidx = (lane < c2) ? csr_src[base + 64 + lane] : 0;
        }
    }
    acc.x += a0.x + a1.x;
    acc.y += a0.y + a1.y;
}

// ---------------- init ----------------
__global__ void k_init(int* degi, float* pooled, float* counts) {
    int i = blockIdx.x * 256 + threadIdx.x;
    if (i < NPAD) degi[i] = 0;
    if (i < NUM_GRAPHS * DIM) pooled[i] = 0.0f;
    if (i < NUM_GRAPHS) counts[i] = 0.0f;
}

// ---------------- W -> Wt bf16 transpose (all 3 layers) ----------------
__global__ void k_prep(const float* __restrict__ W1, const float* __restrict__ W2,
                       const float* __restrict__ W3, ushort_t* __restrict__ Wt) {
    int i = blockIdx.x * 256 + threadIdx.x;
    int mat = i >> 14;
    int idx = i & 16383;
    const float* W = (mat == 0) ? W1 : (mat == 1) ? W2 : W3;
    int n = idx >> 7, k = idx & 127;
    Wt[mat * 16384 + n * 128 + k] = f2bf(W[k * 128 + n]);
}

// ---------------- degree histogram; atomic return = within-row rank ----------------
__global__ void k_count(const int* __restrict__ dst, int* degi, int* rank, int nedges) {
    int e = blockIdx.x * 256 + threadIdx.x;
    if (e < nedges) rank[e] = atomicAdd(&degi[dst[e]], 1);
}

// ---------------- scan ----------------
__global__ __launch_bounds__(256) void k_scan1(const int* __restrict__ degi,
                                               int* rowptr, int* bsum) {
    __shared__ int sh[256];
    int i = blockIdx.x * 256 + threadIdx.x;
    int v = degi[i];
    sh[threadIdx.x] = v;
    __syncthreads();
    for (int off = 1; off < 256; off <<= 1) {
        int t = (threadIdx.x >= off) ? sh[threadIdx.x - off] : 0;
        __syncthreads();
        sh[threadIdx.x] += t;
        __syncthreads();
    }
    rowptr[i] = sh[threadIdx.x] - v;
    if (threadIdx.x == 255) bsum[blockIdx.x] = sh[255];
}

__global__ __launch_bounds__(256) void k_scan2(int* bsum, int nblocks) {
    __shared__ int sh[256];
    int v = (threadIdx.x < nblocks) ? bsum[threadIdx.x] : 0;
    sh[threadIdx.x] = v;
    __syncthreads();
    for (int off = 1; off < 256; off <<= 1) {
        int t = (threadIdx.x >= off) ? sh[threadIdx.x - off] : 0;
        __syncthreads();
        sh[threadIdx.x] += t;
        __syncthreads();
    }
    if (threadIdx.x < nblocks) bsum[threadIdx.x] = sh[threadIdx.x] - v;
}

__global__ __launch_bounds__(256) void k_scan3(int* rowptr, const int* __restrict__ bsum,
                                               const int* __restrict__ degi,
                                               float* dinv) {
    int i = blockIdx.x * 256 + threadIdx.x;
    rowptr[i] = rowptr[i] + bsum[blockIdx.x];
    if (i < N_NODES) dinv[i] = rsqrtf((float)degi[i] + 1.0f);
}

// ---------------- CSR fill: atomic-free scatter via precomputed rank ----------------
__global__ void k_fill(const int* __restrict__ src, const int* __restrict__ dst,
                       const int* __restrict__ rank, const int* __restrict__ rowptr,
                       int* csr_src, int nedges) {
    int e = blockIdx.x * 256 + threadIdx.x;
    if (e < nedges) csr_src[rowptr[dst[e]] + rank[e]] = src[e];
}

// ---------------- layer-1 matmul: Tb1' = (x @ W1) * dinv[row] ----------------
__global__ __launch_bounds__(256) void k_mm1(
    const float* __restrict__ xin, const ushort_t* __restrict__ WtG,
    const float* __restrict__ dinv, ushort_t* __restrict__ TbOut)
{
    __shared__ ushort_t Wl[DIM * XPITCH];
    __shared__ ushort_t Xl[64 * XPITCH];

    const int tid = threadIdx.x;
    const int rowbase = blockIdx.x * 64;

    #pragma unroll
    for (int i = 0; i < 8; ++i) {
        int g = tid + i * 256;
        uint4 v = ((const uint4*)WtG)[g];
        *((uint4*)&Wl[(g >> 4) * XPITCH + (g & 15) * 8]) = v;
    }
    #pragma unroll
    for (int i = 0; i < 8; ++i) {
        int c = tid + i * 256;
        int row = c >> 5;
        int grow = rowbase + row;
        float4 f = make_float4(0.f, 0.f, 0.f, 0.f);
        if (grow < N_NODES)
            f = ((const float4*)xin)[(long long)rowbase * 32 + c];
        ushort4 h;
        h.x = f2bf(f.x); h.y = f2bf(f.y); h.z = f2bf(f.z); h.w = f2bf(f.w);
        *((ushort4*)&Xl[row * XPITCH + (c & 31) * 4]) = h;
    }
    __syncthreads();

    const int wave = tid >> 6;
    const int lane = tid & 63;
    const int quad = lane >> 4;
    const int lm   = lane & 15;
    const int m0   = wave * 16;

    short8 af[4];
    #pragma unroll
    for (int k0 = 0; k0 < 4; ++k0)
        af[k0] = *(const short8*)&Xl[(m0 + lm) * XPITCH + k0 * 32 + quad * 8];

    int noder[4]; float di[4]; bool okr[4];
    #pragma unroll
    for (int r = 0; r < 4; ++r) {
        noder[r] = rowbase + m0 + quad * 4 + r;
        okr[r] = (noder[r] < N_NODES);
        di[r] = okr[r] ? dinv[noder[r]] : 0.f;
    }

    for (int n0 = 0; n0 < DIM; n0 += 16) {
        f32x4 acc = {0.f, 0.f, 0.f, 0.f};
        #pragma unroll
        for (int k0 = 0; k0 < 4; ++k0) {
            short8 bf = *(const short8*)&Wl[(n0 + lm) * XPITCH + k0 * 32 + quad * 8];
            acc = __builtin_amdgcn_mfma_f32_16x16x32_bf16(af[k0], bf, acc, 0, 0, 0);
        }
        int n = n0 + lm;
        #pragma unroll
        for (int r = 0; r < 4; ++r)
            if (okr[r])
                TbOut[(long long)noder[r] * DIM + n] = f2bf(acc[r] * di[r]);
    }
}

// ---------------- fused: X = ReLU(b + dinv[n]*Sum Tb'[s]) ; Tb_out' = (X@W)*dinv ----------------
// Round-0 structure; gather core swapped to readlane-fed (idx via one coalesced
// load, prefetched one node ahead so it never sits on the row-load path).
__global__ __launch_bounds__(256) void k_fused(
    const int* __restrict__ rowptr, const int* __restrict__ csr_src,
    const float* __restrict__ dinv, const uint_t* __restrict__ TbIn,
    const ushort_t* __restrict__ WtG, const float* __restrict__ b_prev,
    ushort_t* __restrict__ TbOut)
{
    __shared__ ushort_t Xl[16 * XPITCH];   // 4352 B

    const int tid = threadIdx.x;
    const int rowbase = blockIdx.x * 16;
    const int wave = tid >> 6;
    const int lane = tid & 63;

    float2 bias2 = ((const float2*)b_prev)[lane];

    // rowptr for this wave's 4 nodes: one coalesced load + readlane
    const int nfirst = rowbase + wave * 4;
    int pv = (lane < 5) ? rowptr[nfirst + lane] : 0;
    int p[5];
    #pragma unroll
    for (int i = 0; i < 5; ++i) p[i] = __builtin_amdgcn_readlane(pv, i);

    // prefetch node 0's index vector
    int idx_n;
    {
        int d0 = p[1] - p[0];
        idx_n = (lane < d0) ? csr_src[p[0] + lane] : 0;
    }

    #pragma unroll
    for (int t = 0; t < 4; ++t) {
        int idx_cur = idx_n;
        if (t < 3) {                        // prefetch next node's indices
            int dn = p[t + 2] - p[t + 1];
            idx_n = (lane < dn) ? csr_src[p[t + 1] + lane] : 0;
        }
        int r = wave * 4 + t;
        int n = rowbase + r;
        float2 acc = make_float2(0.f, 0.f);
        float dd = 0.f;
        if (n < N_NODES) {
            dd = dinv[n];
            gather_rl(n, lane, idx_cur, p[t], p[t + 1], csr_src, TbIn, acc);
        }
        ushort2 h;
        h.x = f2bf(fmaxf(bias2.x + acc.x * dd, 0.f));
        h.y = f2bf(fmaxf(bias2.y + acc.y * dd, 0.f));
        *((ushort2*)&Xl[r * XPITCH + lane * 2]) = h;
    }
    __syncthreads();

    const int quad = lane >> 4;
    const int lm   = lane & 15;

    short8 af[4];
    #pragma unroll
    for (int k0 = 0; k0 < 4; ++k0)
        af[k0] = *(const short8*)&Xl[lm * XPITCH + k0 * 32 + quad * 8];

    int noder[4]; float di[4]; bool okr[4];
    #pragma unroll
    for (int r = 0; r < 4; ++r) {
        noder[r] = rowbase + quad * 4 + r;
        okr[r] = (noder[r] < N_NODES);
        di[r] = okr[r] ? dinv[noder[r]] : 0.f;
    }

    #pragma unroll
    for (int h = 0; h < 2; ++h) {
        int n0 = wave * 32 + h * 16;
        f32x4 acc = {0.f, 0.f, 0.f, 0.f};
        #pragma unroll
        for (int k0 = 0; k0 < 4; ++k0) {
            short8 bf = *(const short8*)&WtG[(n0 + lm) * DIM + k0 * 32 + quad * 8];
            acc = __builtin_amdgcn_mfma_f32_16x16x32_bf16(af[k0], bf, acc, 0, 0, 0);
        }
        int n = n0 + lm;
        #pragma unroll
        for (int r = 0; r < 4; ++r)
            if (okr[r])
                TbOut[(long long)noder[r] * DIM + n] = f2bf(acc[r] * di[r]);
    }
}

// ---------------- fused gather + mean-pool, LDS flush accumulation ----------------
// Round-0 8-row strips; readlane gather core + idx prefetch across nodes.
__global__ __launch_bounds__(256) void k_poolgather(
    const int* __restrict__ rowptr, const int* __restrict__ csr_src,
    const float* __restrict__ dinv, const uint_t* __restrict__ Tb,
    const float* __restrict__ b3, const int* __restrict__ batch,
    float* pooled, float* counts)
{
    __shared__ float lp[8][DIM];   // 4 KB
    __shared__ float lc[8];

    const int tid  = threadIdx.x;
    const int wave = tid >> 6;
    const int lane = tid & 63;
    const int blk0 = blockIdx.x * 32;

    #pragma unroll
    for (int i = 0; i < 4; ++i) ((float*)lp)[tid + i * 256] = 0.f;
    if (tid < 8) lc[tid] = 0.f;
    __syncthreads();

    const int gbase = batch[min(blk0, N_NODES - 1)];
    int n0 = blk0 + wave * 8;

    if (n0 < N_NODES) {
        int nend = min(n0 + 8, N_NODES);
        float2 bias2 = ((const float2*)b3)[lane];

        int pv = (lane < 9) ? rowptr[min(n0 + lane, NPAD)] : 0;
        int p[9];
        #pragma unroll
        for (int i = 0; i < 9; ++i) p[i] = __builtin_amdgcn_readlane(pv, i);

        int cur = batch[n0];
        int runstart = n0;
        float2 pacc = make_float2(0.f, 0.f);

        int idx_n;
        {
            int d0 = p[1] - p[0];
            idx_n = (lane < d0) ? csr_src[p[0] + lane] : 0;
        }

        for (int i = 0; i < nend - n0; ++i) {
            int n = n0 + i;
            int idx_cur = idx_n;
            if (i < 7) {
                int dn = p[i + 2] - p[i + 1];
                idx_n = (lane < dn) ? csr_src[p[i + 1] + lane] : 0;
            }
            int g = batch[n];
            if (g != cur) {
                int slot = cur - gbase;
                if (slot < 8) {
                    atomicAdd(&lp[slot][2 * lane], pacc.x);
                    atomicAdd(&lp[slot][2 * lane + 1], pacc.y);
                    if (lane == 0) atomicAdd(&lc[slot], (float)(n - runstart));
                } else {
                    atomicAdd(&pooled[cur * DIM + 2 * lane], pacc.x);
                    atomicAdd(&pooled[cur * DIM + 2 * lane + 1], pacc.y);
                    if (lane == 0) atomicAdd(&counts[cur], (float)(n - runstart));
                }
                pacc.x = 0.f; pacc.y = 0.f; cur = g; runstart = n;
            }
            float2 acc = make_float2(0.f, 0.f);
            gather_rl(n, lane, idx_cur, p[i], p[i + 1], csr_src, Tb, acc);
            float dd = dinv[n];
            pacc.x += bias2.x + acc.x * dd;
            pacc.y += bias2.y + acc.y * dd;
        }
        int slot = cur - gbase;
        if (slot < 8) {
            atomicAdd(&lp[slot][2 * lane], pacc.x);
            atomicAdd(&lp[slot][2 * lane + 1], pacc.y);
            if (lane == 0) atomicAdd(&lc[slot], (float)(nend - runstart));
        } else {
            atomicAdd(&pooled[cur * DIM + 2 * lane], pacc.x);
            atomicAdd(&pooled[cur * DIM + 2 * lane + 1], pacc.y);
            if (lane == 0) atomicAdd(&counts[cur], (float)(nend - runstart));
        }
    }
    __syncthreads();

    #pragma unroll
    for (int s = 0; s < 8; ++s) {
        if (lc[s] != 0.f) {
            if (tid < DIM) atomicAdd(&pooled[(gbase + s) * DIM + tid], lp[s][tid]);
            if (tid == DIM) atomicAdd(&counts[gbase + s], lc[s]);
        }
    }
}

// ---------------- classifier head ----------------
__global__ __launch_bounds__(128) void k_cls(
    const float* __restrict__ pooled, const float* __restrict__ counts,
    const float* __restrict__ C1, const float* __restrict__ bc1,
    const float* __restrict__ C2, const float* __restrict__ bc2,
    float* out)
{
    __shared__ float pm[DIM];
    __shared__ float gv[DIM];
    int g = blockIdx.x, j = threadIdx.x;
    float cnt = fmaxf(counts[g], 1.0f);
    pm[j] = pooled[g * DIM + j] / cnt;
    __syncthreads();
    float a = bc1[j];
    for (int k = 0; k < DIM; ++k) a += pm[k] * C1[k * DIM + j];
    gv[j] = fmaxf(a, 0.f);
    __syncthreads();
    if (j < NUM_CLASSES) {
        float o = bc2[j];
        for (int k = 0; k < DIM; ++k) o += gv[k] * C2[k * NUM_CLASSES + j];
        out[g * NUM_CLASSES + j] = o;
    }
}

extern "C" void kernel_launch(void* const* d_in, const int* in_sizes, int n_in,
                              void* d_out, int out_size, void* d_ws, size_t ws_size,
                              hipStream_t stream) {
    const float* x    = (const float*)d_in[0];
    const int*   ei   = (const int*)d_in[1];
    const int*   batch= (const int*)d_in[2];
    const float* W1   = (const float*)d_in[3];
    const float* b1   = (const float*)d_in[4];
    const float* W2   = (const float*)d_in[5];
    const float* b2   = (const float*)d_in[6];
    const float* W3   = (const float*)d_in[7];
    const float* b3   = (const float*)d_in[8];
    const float* C1   = (const float*)d_in[9];
    const float* bc1  = (const float*)d_in[10];
    const float* C2   = (const float*)d_in[11];
    const float* bc2  = (const float*)d_in[12];

    const int nedges = in_sizes[1] / 2;
    const int* src = ei;
    const int* dst = ei + nedges;

    // workspace layout (4-byte units)
    float*    dinv    = (float*)d_ws;                           // NPAD
    uint_t*   TbA     = (uint_t*)(dinv + NPAD);                 // N_NODES*64
    uint_t*   TbB     = TbA + (long long)N_NODES * 64;          // N_NODES*64
    float*    pooled  = (float*)(TbB + (long long)N_NODES * 64);// 8192
    float*    counts  = pooled + NUM_GRAPHS * DIM;              // 64
    int*      degi    = (int*)(counts + 64);                    // NPAD
    int*      rowptr  = degi + NPAD;                            // NPAD+256
    int*      bsum    = rowptr + NPAD + 256;                    // 256
    int*      rank    = bsum + 256;                             // nedges
    int*      csr_src = rank + nedges;                          // nedges
    ushort_t* Wt      = (ushort_t*)(csr_src + nedges);          // 3*16384 bf16

    const int nodeBlocks = NPAD / 256;                     // 196
    const int mmBlocks   = (N_NODES + 63) / 64;            // 782
    const int fusedBlocks= (N_NODES + 15) / 16;            // 3125
    const int pgBlocks   = (N_NODES + 31) / 32;            // 1563
    const int edgeBlocks = (nedges + 255) / 256;           // 3125

    k_init<<<nodeBlocks, 256, 0, stream>>>(degi, pooled, counts);
    k_prep<<<192, 256, 0, stream>>>(W1, W2, W3, Wt);
    k_count<<<edgeBlocks, 256, 0, stream>>>(dst, degi, rank, nedges);
    k_scan1<<<nodeBlocks, 256, 0, stream>>>(degi, rowptr, bsum);
    k_scan2<<<1, 256, 0, stream>>>(bsum, nodeBlocks);
    k_scan3<<<nodeBlocks, 256, 0, stream>>>(rowptr, bsum, degi, dinv);
    k_fill<<<edgeBlocks, 256, 0, stream>>>(src, dst, rank, rowptr, csr_src, nedges);

    k_mm1<<<mmBlocks, 256, 0, stream>>>(x, Wt, dinv, (ushort_t*)TbA);
    k_fused<<<fusedBlocks, 256, 0, stream>>>(rowptr, csr_src, dinv, TbA,
                                             Wt + 16384, b1, (ushort_t*)TbB);
    k_fused<<<fusedBlocks, 256, 0, stream>>>(rowptr, csr_src, dinv, TbB,
                                             Wt + 32768, b2, (ushort_t*)TbA);
    k_poolgather<<<pgBlocks, 256, 0, stream>>>(rowptr, csr_src, dinv, TbA,
                                               b3, batch, pooled, counts);
    k_cls<<<NUM_GRAPHS, 128, 0, stream>>>(pooled, counts, C1, bc1, C2, bc2,
                                          (float*)d_out);
}

// Round 8
// 291.037 us; speedup vs baseline: 1.3861x; 1.0137x over previous
//
#include <hip/hip_runtime.h>
#include <hip/hip_bf16.h>

#define N_NODES    50000
#define DIM        128
#define NUM_GRAPHS 64
#define NUM_CLASSES 3
#define NPAD       50176   // 196*256
#define XPITCH     136     // LDS row pitch in ushorts (17 x 16B, odd -> conflict-free b128)

typedef unsigned short ushort_t;
typedef unsigned int   uint_t;
typedef __attribute__((ext_vector_type(8))) short short8;
typedef __attribute__((ext_vector_type(4))) float f32x4;

__device__ __forceinline__ ushort_t f2bf(float f) {
    union { float f; uint_t u; } v; v.f = f;
    uint_t r = v.u + 0x7fffu + ((v.u >> 16) & 1u);   // RNE
    return (ushort_t)(r >> 16);
}
__device__ __forceinline__ float bflo(uint_t u) {
    union { uint_t u; float f; } v; v.u = u << 16; return v.f;
}
__device__ __forceinline__ float bfhi(uint_t u) {
    union { uint_t u; float f; } v; v.u = u & 0xffff0000u; return v.f;
}

// Paired-lane readlane-fed gather. Half h = lane>>5 takes edge 2q+h of each
// pair; lane m = lane&31 holds channels 4m..4m+3 as one dwordx2 (8 B). One
// VMEM inst covers TWO edges (512 B) -- half the per-edge issue cost of the
// round-7 winner, same 8-edge batch double-buffer, same idx-prefetch. Caller
// must shfl_xor(32)-reduce the two half-wave partials and add the self row.
__device__ __forceinline__ void pair_gather(
    int lane, int h, int m, int myidx0, int p0, int p1,
    const int* __restrict__ csr_src, const uint2* __restrict__ Tb2,
    float4& A)
{
    float ax0=0.f, ay0=0.f, az0=0.f, aw0=0.f;   // dual accumulation chains
    float ax1=0.f, ay1=0.f, az1=0.f, aw1=0.f;
    int deg = p1 - p0;
    if (deg < 0) deg = 0;
    int nchunk = (deg + 63) >> 6;
    int myidx = myidx0;
    for (int ck = 0; ck < nchunk; ++ck) {
        int base = p0 + (ck << 6);
        int cnt = p1 - base; if (cnt > 64) cnt = 64;
        int nb = cnt >> 3;                     // batches of 8 edges = 4 pair-loads
        if (nb > 0) {
            uint2 ucur[4];
            #pragma unroll
            for (int q = 0; q < 4; ++q) {
                int s0 = __builtin_amdgcn_readlane(myidx, 2 * q);
                int s1 = __builtin_amdgcn_readlane(myidx, 2 * q + 1);
                int s  = h ? s1 : s0;
                ucur[q] = Tb2[s * 32 + m];
            }
            for (int b = 1; b < nb; ++b) {
                int jb = b * 8;
                uint2 unxt[4];
                #pragma unroll
                for (int q = 0; q < 4; ++q) {
                    int s0 = __builtin_amdgcn_readlane(myidx, jb + 2 * q);
                    int s1 = __builtin_amdgcn_readlane(myidx, jb + 2 * q + 1);
                    int s  = h ? s1 : s0;
                    unxt[q] = Tb2[s * 32 + m];
                }
                #pragma unroll
                for (int q = 0; q < 4; q += 2) {
                    ax0 += bflo(ucur[q].x);     ay0 += bfhi(ucur[q].x);
                    az0 += bflo(ucur[q].y);     aw0 += bfhi(ucur[q].y);
                    ax1 += bflo(ucur[q + 1].x); ay1 += bfhi(ucur[q + 1].x);
                    az1 += bflo(ucur[q + 1].y); aw1 += bfhi(ucur[q + 1].y);
                }
                #pragma unroll
                for (int q = 0; q < 4; ++q) ucur[q] = unxt[q];
            }
            #pragma unroll
            for (int q = 0; q < 4; q += 2) {
                ax0 += bflo(ucur[q].x);     ay0 += bfhi(ucur[q].x);
                az0 += bflo(ucur[q].y);     aw0 += bfhi(ucur[q].y);
                ax1 += bflo(ucur[q + 1].x); ay1 += bfhi(ucur[q + 1].x);
                az1 += bflo(ucur[q + 1].y); aw1 += bfhi(ucur[q + 1].y);
            }
        }
        int j = nb * 8;
        for (; j + 2 <= cnt; j += 2) {         // tail pairs
            int s0 = __builtin_amdgcn_readlane(myidx, j);
            int s1 = __builtin_amdgcn_readlane(myidx, j + 1);
            int s  = h ? s1 : s0;
            uint2 u = Tb2[s * 32 + m];
            ax0 += bflo(u.x); ay0 += bfhi(u.x);
            az0 += bflo(u.y); aw0 += bfhi(u.y);
        }
        if (j < cnt) {                         // odd tail edge: half 0 only
            int s = __builtin_amdgcn_readlane(myidx, j);
            uint2 u = Tb2[s * 32 + m];
            if (!h) {
                ax0 += bflo(u.x); ay0 += bfhi(u.x);
                az0 += bflo(u.y); aw0 += bfhi(u.y);
            }
        }
        if (ck + 1 < nchunk) {                 // rare: degree > 64
            int c2 = p1 - (base + 64);
            myidx = (lane < c2) ? csr_src[base + 64 + lane] : 0;
        }
    }
    A.x += ax0 + ax1;
    A.y += ay0 + ay1;
    A.z += az0 + az1;
    A.w += aw0 + aw1;
}

// ---------------- init ----------------
__global__ void k_init(int* degi, float* pooled, float* counts) {
    int i = blockIdx.x * 256 + threadIdx.x;
    if (i < NPAD) degi[i] = 0;
    if (i < NUM_GRAPHS * DIM) pooled[i] = 0.0f;
    if (i < NUM_GRAPHS) counts[i] = 0.0f;
}

// ---------------- W -> Wt bf16 transpose (all 3 layers) ----------------
__global__ void k_prep(const float* __restrict__ W1, const float* __restrict__ W2,
                       const float* __restrict__ W3, ushort_t* __restrict__ Wt) {
    int i = blockIdx.x * 256 + threadIdx.x;
    int mat = i >> 14;
    int idx = i & 16383;
    const float* W = (mat == 0) ? W1 : (mat == 1) ? W2 : W3;
    int n = idx >> 7, k = idx & 127;
    Wt[mat * 16384 + n * 128 + k] = f2bf(W[k * 128 + n]);
}

// ---------------- degree histogram; atomic return = within-row rank ----------------
__global__ void k_count(const int* __restrict__ dst, int* degi, int* rank, int nedges) {
    int e = blockIdx.x * 256 + threadIdx.x;
    if (e < nedges) rank[e] = atomicAdd(&degi[dst[e]], 1);
}

// ---------------- scan ----------------
__global__ __launch_bounds__(256) void k_scan1(const int* __restrict__ degi,
                                               int* rowptr, int* bsum) {
    __shared__ int sh[256];
    int i = blockIdx.x * 256 + threadIdx.x;
    int v = degi[i];
    sh[threadIdx.x] = v;
    __syncthreads();
    for (int off = 1; off < 256; off <<= 1) {
        int t = (threadIdx.x >= off) ? sh[threadIdx.x - off] : 0;
        __syncthreads();
        sh[threadIdx.x] += t;
        __syncthreads();
    }
    rowptr[i] = sh[threadIdx.x] - v;
    if (threadIdx.x == 255) bsum[blockIdx.x] = sh[255];
}

__global__ __launch_bounds__(256) void k_scan2(int* bsum, int nblocks) {
    __shared__ int sh[256];
    int v = (threadIdx.x < nblocks) ? bsum[threadIdx.x] : 0;
    sh[threadIdx.x] = v;
    __syncthreads();
    for (int off = 1; off < 256; off <<= 1) {
        int t = (threadIdx.x >= off) ? sh[threadIdx.x - off] : 0;
        __syncthreads();
        sh[threadIdx.x] += t;
        __syncthreads();
    }
    if (threadIdx.x < nblocks) bsum[threadIdx.x] = sh[threadIdx.x] - v;
}

__global__ __launch_bounds__(256) void k_scan3(int* rowptr, const int* __restrict__ bsum,
                                               const int* __restrict__ degi,
                                               float* dinv) {
    int i = blockIdx.x * 256 + threadIdx.x;
    rowptr[i] = rowptr[i] + bsum[blockIdx.x];
    if (i < N_NODES) dinv[i] = rsqrtf((float)degi[i] + 1.0f);
}

// ---------------- CSR fill: atomic-free scatter via precomputed rank ----------------
__global__ void k_fill(const int* __restrict__ src, const int* __restrict__ dst,
                       const int* __restrict__ rank, const int* __restrict__ rowptr,
                       int* csr_src, int nedges) {
    int e = blockIdx.x * 256 + threadIdx.x;
    if (e < nedges) csr_src[rowptr[dst[e]] + rank[e]] = src[e];
}

// ---------------- layer-1 matmul: Tb1' = (x @ W1) * dinv[row] ----------------
__global__ __launch_bounds__(256) void k_mm1(
    const float* __restrict__ xin, const ushort_t* __restrict__ WtG,
    const float* __restrict__ dinv, ushort_t* __restrict__ TbOut)
{
    __shared__ ushort_t Wl[DIM * XPITCH];
    __shared__ ushort_t Xl[64 * XPITCH];

    const int tid = threadIdx.x;
    const int rowbase = blockIdx.x * 64;

    #pragma unroll
    for (int i = 0; i < 8; ++i) {
        int g = tid + i * 256;
        uint4 v = ((const uint4*)WtG)[g];
        *((uint4*)&Wl[(g >> 4) * XPITCH + (g & 15) * 8]) = v;
    }
    #pragma unroll
    for (int i = 0; i < 8; ++i) {
        int c = tid + i * 256;
        int row = c >> 5;
        int grow = rowbase + row;
        float4 f = make_float4(0.f, 0.f, 0.f, 0.f);
        if (grow < N_NODES)
            f = ((const float4*)xin)[(long long)rowbase * 32 + c];
        ushort4 h;
        h.x = f2bf(f.x); h.y = f2bf(f.y); h.z = f2bf(f.z); h.w = f2bf(f.w);
        *((ushort4*)&Xl[row * XPITCH + (c & 31) * 4]) = h;
    }
    __syncthreads();

    const int wave = tid >> 6;
    const int lane = tid & 63;
    const int quad = lane >> 4;
    const int lm   = lane & 15;
    const int m0   = wave * 16;

    short8 af[4];
    #pragma unroll
    for (int k0 = 0; k0 < 4; ++k0)
        af[k0] = *(const short8*)&Xl[(m0 + lm) * XPITCH + k0 * 32 + quad * 8];

    int noder[4]; float di[4]; bool okr[4];
    #pragma unroll
    for (int r = 0; r < 4; ++r) {
        noder[r] = rowbase + m0 + quad * 4 + r;
        okr[r] = (noder[r] < N_NODES);
        di[r] = okr[r] ? dinv[noder[r]] : 0.f;
    }

    for (int n0 = 0; n0 < DIM; n0 += 16) {
        f32x4 acc = {0.f, 0.f, 0.f, 0.f};
        #pragma unroll
        for (int k0 = 0; k0 < 4; ++k0) {
            short8 bf = *(const short8*)&Wl[(n0 + lm) * XPITCH + k0 * 32 + quad * 8];
            acc = __builtin_amdgcn_mfma_f32_16x16x32_bf16(af[k0], bf, acc, 0, 0, 0);
        }
        int n = n0 + lm;
        #pragma unroll
        for (int r = 0; r < 4; ++r)
            if (okr[r])
                TbOut[(long long)noder[r] * DIM + n] = f2bf(acc[r] * di[r]);
    }
}

// ---------------- fused: X = ReLU(b + dinv[n]*Sum Tb'[s]) ; Tb_out' = (X@W)*dinv ----------------
// Round-7 structure; gather core swapped to paired-lane (1 VMEM inst / 2 edges).
__global__ __launch_bounds__(256) void k_fused(
    const int* __restrict__ rowptr, const int* __restrict__ csr_src,
    const float* __restrict__ dinv, const uint_t* __restrict__ TbIn,
    const ushort_t* __restrict__ WtG, const float* __restrict__ b_prev,
    ushort_t* __restrict__ TbOut)
{
    __shared__ ushort_t Xl[16 * XPITCH];   // 4352 B

    const int tid = threadIdx.x;
    const int rowbase = blockIdx.x * 16;
    const int wave = tid >> 6;
    const int lane = tid & 63;
    const int h    = lane >> 5;
    const int m    = lane & 31;
    const uint2* Tb2 = (const uint2*)TbIn;

    float2 bias2 = ((const float2*)b_prev)[2 * m + h];

    // rowptr for this wave's 4 nodes: one coalesced load + readlane
    const int nfirst = rowbase + wave * 4;
    int pv = (lane < 5) ? rowptr[nfirst + lane] : 0;
    int p[5];
    #pragma unroll
    for (int i = 0; i < 5; ++i) p[i] = __builtin_amdgcn_readlane(pv, i);

    // prefetch node 0's index vector
    int idx_n;
    {
        int d0 = p[1] - p[0];
        idx_n = (lane < d0) ? csr_src[p[0] + lane] : 0;
    }

    #pragma unroll
    for (int t = 0; t < 4; ++t) {
        int idx_cur = idx_n;
        if (t < 3) {                        // prefetch next node's indices
            int dn = p[t + 2] - p[t + 1];
            idx_n = (lane < dn) ? csr_src[p[t + 1] + lane] : 0;
        }
        int r = wave * 4 + t;
        int n = rowbase + r;
        float4 a = make_float4(0.f, 0.f, 0.f, 0.f);
        float dd = 0.f;
        uint2 us = make_uint2(0u, 0u);
        if (n < N_NODES) {
            us = Tb2[n * 32 + m];           // self row (issues first)
            dd = dinv[n];
            pair_gather(lane, h, m, idx_cur, p[t], p[t + 1], csr_src, Tb2, a);
        }
        // merge half-wave partials (whole wave participates; n is wave-uniform)
        a.x += __shfl_xor(a.x, 32);
        a.y += __shfl_xor(a.y, 32);
        a.z += __shfl_xor(a.z, 32);
        a.w += __shfl_xor(a.w, 32);
        a.x += bflo(us.x); a.y += bfhi(us.x);   // self counted once (post-merge)
        a.z += bflo(us.y); a.w += bfhi(us.y);
        float o0 = h ? a.z : a.x;               // owned channels 4m+2h, +1
        float o1 = h ? a.w : a.y;
        ushort2 hh;
        hh.x = f2bf(fmaxf(bias2.x + o0 * dd, 0.f));
        hh.y = f2bf(fmaxf(bias2.y + o1 * dd, 0.f));
        *((ushort2*)&Xl[r * XPITCH + 4 * m + 2 * h]) = hh;
    }
    __syncthreads();

    const int quad = lane >> 4;
    const int lm   = lane & 15;

    short8 af[4];
    #pragma unroll
    for (int k0 = 0; k0 < 4; ++k0)
        af[k0] = *(const short8*)&Xl[lm * XPITCH + k0 * 32 + quad * 8];

    int noder[4]; float di[4]; bool okr[4];
    #pragma unroll
    for (int r = 0; r < 4; ++r) {
        noder[r] = rowbase + quad * 4 + r;
        okr[r] = (noder[r] < N_NODES);
        di[r] = okr[r] ? dinv[noder[r]] : 0.f;
    }

    #pragma unroll
    for (int hh = 0; hh < 2; ++hh) {
        int n0 = wave * 32 + hh * 16;
        f32x4 acc = {0.f, 0.f, 0.f, 0.f};
        #pragma unroll
        for (int k0 = 0; k0 < 4; ++k0) {
            short8 bf = *(const short8*)&WtG[(n0 + lm) * DIM + k0 * 32 + quad * 8];
            acc = __builtin_amdgcn_mfma_f32_16x16x32_bf16(af[k0], bf, acc, 0, 0, 0);
        }
        int n = n0 + lm;
        #pragma unroll
        for (int r = 0; r < 4; ++r)
            if (okr[r])
                TbOut[(long long)noder[r] * DIM + n] = f2bf(acc[r] * di[r]);
    }
}

// ---------------- fused gather + mean-pool, LDS flush accumulation ----------------
// Round-7 8-row strips; paired-lane gather core + idx prefetch across nodes.
// Lane owns channels ch = 4m+2h, ch+1 for the run accumulator / flushes.
__global__ __launch_bounds__(256) void k_poolgather(
    const int* __restrict__ rowptr, const int* __restrict__ csr_src,
    const float* __restrict__ dinv, const uint_t* __restrict__ Tb,
    const float* __restrict__ b3, const int* __restrict__ batch,
    float* pooled, float* counts)
{
    __shared__ float lp[8][DIM];   // 4 KB
    __shared__ float lc[8];

    const int tid  = threadIdx.x;
    const int wave = tid >> 6;
    const int lane = tid & 63;
    const int h    = lane >> 5;
    const int m    = lane & 31;
    const int blk0 = blockIdx.x * 32;
    const uint2* Tb2 = (const uint2*)Tb;
    const int ch = 4 * m + 2 * h;

    #pragma unroll
    for (int i = 0; i < 4; ++i) ((float*)lp)[tid + i * 256] = 0.f;
    if (tid < 8) lc[tid] = 0.f;
    __syncthreads();

    const int gbase = batch[min(blk0, N_NODES - 1)];
    int n0 = blk0 + wave * 8;

    if (n0 < N_NODES) {
        int nend = min(n0 + 8, N_NODES);
        float2 bias2 = ((const float2*)b3)[2 * m + h];

        int pv = (lane < 9) ? rowptr[min(n0 + lane, NPAD)] : 0;
        int p[9];
        #pragma unroll
        for (int i = 0; i < 9; ++i) p[i] = __builtin_amdgcn_readlane(pv, i);

        int cur = batch[n0];
        int runstart = n0;
        float2 pacc = make_float2(0.f, 0.f);

        int idx_n;
        {
            int d0 = p[1] - p[0];
            idx_n = (lane < d0) ? csr_src[p[0] + lane] : 0;
        }

        for (int i = 0; i < nend - n0; ++i) {
            int n = n0 + i;
            int idx_cur = idx_n;
            if (i < 7) {
                int dn = p[i + 2] - p[i + 1];
                idx_n = (lane < dn) ? csr_src[p[i + 1] + lane] : 0;
            }
            int g = batch[n];
            if (g != cur) {
                int slot = cur - gbase;
                if (slot < 8) {
                    atomicAdd(&lp[slot][ch], pacc.x);
                    atomicAdd(&lp[slot][ch + 1], pacc.y);
                    if (lane == 0) atomicAdd(&lc[slot], (float)(n - runstart));
                } else {
                    atomicAdd(&pooled[cur * DIM + ch], pacc.x);
                    atomicAdd(&pooled[cur * DIM + ch + 1], pacc.y);
                    if (lane == 0) atomicAdd(&counts[cur], (float)(n - runstart));
                }
                pacc.x = 0.f; pacc.y = 0.f; cur = g; runstart = n;
            }
            float4 a = make_float4(0.f, 0.f, 0.f, 0.f);
            uint2 us = Tb2[n * 32 + m];
            pair_gather(lane, h, m, idx_cur, p[i], p[i + 1], csr_src, Tb2, a);
            a.x += __shfl_xor(a.x, 32);
            a.y += __shfl_xor(a.y, 32);
            a.z += __shfl_xor(a.z, 32);
            a.w += __shfl_xor(a.w, 32);
            a.x += bflo(us.x); a.y += bfhi(us.x);
            a.z += bflo(us.y); a.w += bfhi(us.y);
            float o0 = h ? a.z : a.x;
            float o1 = h ? a.w : a.y;
            float dd = dinv[n];
            pacc.x += bias2.x + o0 * dd;
            pacc.y += bias2.y + o1 * dd;
        }
        int slot = cur - gbase;
        if (slot < 8) {
            atomicAdd(&lp[slot][ch], pacc.x);
            atomicAdd(&lp[slot][ch + 1], pacc.y);
            if (lane == 0) atomicAdd(&lc[slot], (float)(nend - runstart));
        } else {
            atomicAdd(&pooled[cur * DIM + ch], pacc.x);
            atomicAdd(&pooled[cur * DIM + ch + 1], pacc.y);
            if (lane == 0) atomicAdd(&counts[cur], (float)(nend - runstart));
        }
    }
    __syncthreads();

    #pragma unroll
    for (int s = 0; s < 8; ++s) {
        if (lc[s] != 0.f) {
            if (tid < DIM) atomicAdd(&pooled[(gbase + s) * DIM + tid], lp[s][tid]);
            if (tid == DIM) atomicAdd(&counts[gbase + s], lc[s]);
        }
    }
}

// ---------------- classifier head ----------------
__global__ __launch_bounds__(128) void k_cls(
    const float* __restrict__ pooled, const float* __restrict__ counts,
    const float* __restrict__ C1, const float* __restrict__ bc1,
    const float* __restrict__ C2, const float* __restrict__ bc2,
    float* out)
{
    __shared__ float pm[DIM];
    __shared__ float gv[DIM];
    int g = blockIdx.x, j = threadIdx.x;
    float cnt = fmaxf(counts[g], 1.0f);
    pm[j] = pooled[g * DIM + j] / cnt;
    __syncthreads();
    float a = bc1[j];
    for (int k = 0; k < DIM; ++k) a += pm[k] * C1[k * DIM + j];
    gv[j] = fmaxf(a, 0.f);
    __syncthreads();
    if (j < NUM_CLASSES) {
        float o = bc2[j];
        for (int k = 0; k < DIM; ++k) o += gv[k] * C2[k * NUM_CLASSES + j];
        out[g * NUM_CLASSES + j] = o;
    }
}

extern "C" void kernel_launch(void* const* d_in, const int* in_sizes, int n_in,
                              void* d_out, int out_size, void* d_ws, size_t ws_size,
                              hipStream_t stream) {
    const float* x    = (const float*)d_in[0];
    const int*   ei   = (const int*)d_in[1];
    const int*   batch= (const int*)d_in[2];
    const float* W1   = (const float*)d_in[3];
    const float* b1   = (const float*)d_in[4];
    const float* W2   = (const float*)d_in[5];
    const float* b2   = (const float*)d_in[6];
    const float* W3   = (const float*)d_in[7];
    const float* b3   = (const float*)d_in[8];
    const float* C1   = (const float*)d_in[9];
    const float* bc1  = (const float*)d_in[10];
    const float* C2   = (const float*)d_in[11];
    const float* bc2  = (const float*)d_in[12];

    const int nedges = in_sizes[1] / 2;
    const int* src = ei;
    const int* dst = ei + nedges;

    // workspace layout (4-byte units)
    float*    dinv    = (float*)d_ws;                           // NPAD
    uint_t*   TbA     = (uint_t*)(dinv + NPAD);                 // N_NODES*64
    uint_t*   TbB     = TbA + (long long)N_NODES * 64;          // N_NODES*64
    float*    pooled  = (float*)(TbB + (long long)N_NODES * 64);// 8192
    float*    counts  = pooled + NUM_GRAPHS * DIM;              // 64
    int*      degi    = (int*)(counts + 64);                    // NPAD
    int*      rowptr  = degi + NPAD;                            // NPAD+256
    int*      bsum    = rowptr + NPAD + 256;                    // 256
    int*      rank    = bsum + 256;                             // nedges
    int*      csr_src = rank + nedges;                          // nedges
    ushort_t* Wt      = (ushort_t*)(csr_src + nedges);          // 3*16384 bf16

    const int nodeBlocks = NPAD / 256;                     // 196
    const int mmBlocks   = (N_NODES + 63) / 64;            // 782
    const int fusedBlocks= (N_NODES + 15) / 16;            // 3125
    const int pgBlocks   = (N_NODES + 31) / 32;            // 1563
    const int edgeBlocks = (nedges + 255) / 256;           // 3125

    k_init<<<nodeBlocks, 256, 0, stream>>>(degi, pooled, counts);
    k_prep<<<192, 256, 0, stream>>>(W1, W2, W3, Wt);
    k_count<<<edgeBlocks, 256, 0, stream>>>(dst, degi, rank, nedges);
    k_scan1<<<nodeBlocks, 256, 0, stream>>>(degi, rowptr, bsum);
    k_scan2<<<1, 256, 0, stream>>>(bsum, nodeBlocks);
    k_scan3<<<nodeBlocks, 256, 0, stream>>>(rowptr, bsum, degi, dinv);
    k_fill<<<edgeBlocks, 256, 0, stream>>>(src, dst, rank, rowptr, csr_src, nedges);

    k_mm1<<<mmBlocks, 256, 0, stream>>>(x, Wt, dinv, (ushort_t*)TbA);
    k_fused<<<fusedBlocks, 256, 0, stream>>>(rowptr, csr_src, dinv, TbA,
                                             Wt + 16384, b1, (ushort_t*)TbB);
    k_fused<<<fusedBlocks, 256, 0, stream>>>(rowptr, csr_src, dinv, TbB,
                                             Wt + 32768, b2, (ushort_t*)TbA);
    k_poolgather<<<pgBlocks, 256, 0, stream>>>(rowptr, csr_src, dinv, TbA,
                                               b3, batch, pooled, counts);
    k_cls<<<NUM_GRAPHS, 128, 0, stream>>>(pooled, counts, C1, bc1, C2, bc2,
                                          (float*)d_out);
}

// Round 9
// 285.642 us; speedup vs baseline: 1.4122x; 1.0189x over previous
//
#include <hip/hip_runtime.h>
#include <hip/hip_bf16.h>

#define N_NODES    50000
#define DIM        128
#define NUM_GRAPHS 64
#define NUM_CLASSES 3
#define NPAD       50176   // 196*256
#define XPITCH     136     // LDS row pitch in ushorts (17 x 16B, odd -> conflict-free b128)

typedef unsigned short ushort_t;
typedef unsigned int   uint_t;
typedef __attribute__((ext_vector_type(8))) short short8;
typedef __attribute__((ext_vector_type(4))) float f32x4;

__device__ __forceinline__ ushort_t f2bf(float f) {
    union { float f; uint_t u; } v; v.f = f;
    uint_t r = v.u + 0x7fffu + ((v.u >> 16) & 1u);   // RNE
    return (ushort_t)(r >> 16);
}
__device__ __forceinline__ float bflo(uint_t u) {
    union { uint_t u; float f; } v; v.u = u << 16; return v.f;
}
__device__ __forceinline__ float bfhi(uint_t u) {
    union { uint_t u; float f; } v; v.u = u & 0xffff0000u; return v.f;
}

__device__ __forceinline__ void accum8(float* a, uint4 u) {   // static idx only
    a[0] += bflo(u.x); a[1] += bfhi(u.x);
    a[2] += bflo(u.y); a[3] += bfhi(u.y);
    a[4] += bflo(u.z); a[5] += bfhi(u.z);
    a[6] += bflo(u.w); a[7] += bfhi(u.w);
}

// pick this quarter-wave's row index from 4 wave-uniform scalars (3 cndmask)
__device__ __forceinline__ int qsel(int lane, int s0, int s1, int s2, int s3) {
    int lo = (lane & 16) ? s1 : s0;
    int hi = (lane & 16) ? s3 : s2;
    return (lane & 32) ? hi : lo;
}

// Quad-lane readlane-fed gather: quarter q = lane>>4 takes edge 4k+q; lane
// m = lane&15 holds channels 8m..8m+7 as one dwordx4 (16 B). One VMEM inst
// covers FOUR edges (1 KiB) -- half round-8's issue cost. Indices stay
// readlane-fed (no idx VMEM on the batch path -- round-1's failure mode
// avoided); 8-edge batches, 2-deep rotation (4 KB in flight/wave) preserved.
// Caller must shfl_xor(16,32)-reduce the quarter partials + add self row.
__device__ __forceinline__ void quad_gather(
    int lane, int m, int myidx0, int p0, int p1,
    const int* __restrict__ csr_src, const uint4* __restrict__ Tb4,
    float* a)
{
    int deg = p1 - p0;
    if (deg < 0) deg = 0;
    int nchunk = (deg + 63) >> 6;
    int myidx = myidx0;
    for (int ck = 0; ck < nchunk; ++ck) {
        int base = p0 + (ck << 6);
        int cnt = p1 - base; if (cnt > 64) cnt = 64;
        int nb = cnt >> 3;                 // 8-edge batches = 2 quad-loads
        if (nb > 0) {
            uint4 u0, u1;
            {
                int s = qsel(lane, __builtin_amdgcn_readlane(myidx, 0),
                                   __builtin_amdgcn_readlane(myidx, 1),
                                   __builtin_amdgcn_readlane(myidx, 2),
                                   __builtin_amdgcn_readlane(myidx, 3));
                u0 = Tb4[s * 16 + m];
                s = qsel(lane, __builtin_amdgcn_readlane(myidx, 4),
                               __builtin_amdgcn_readlane(myidx, 5),
                               __builtin_amdgcn_readlane(myidx, 6),
                               __builtin_amdgcn_readlane(myidx, 7));
                u1 = Tb4[s * 16 + m];
            }
            for (int b = 1; b < nb; ++b) {
                int jb = b * 8;
                uint4 n0, n1;
                int s = qsel(lane, __builtin_amdgcn_readlane(myidx, jb),
                                   __builtin_amdgcn_readlane(myidx, jb + 1),
                                   __builtin_amdgcn_readlane(myidx, jb + 2),
                                   __builtin_amdgcn_readlane(myidx, jb + 3));
                n0 = Tb4[s * 16 + m];
                s = qsel(lane, __builtin_amdgcn_readlane(myidx, jb + 4),
                               __builtin_amdgcn_readlane(myidx, jb + 5),
                               __builtin_amdgcn_readlane(myidx, jb + 6),
                               __builtin_amdgcn_readlane(myidx, jb + 7));
                n1 = Tb4[s * 16 + m];
                accum8(a, u0); accum8(a, u1);
                u0 = n0; u1 = n1;
            }
            accum8(a, u0); accum8(a, u1);
        }
        int j = nb * 8;
        for (; j + 4 <= cnt; j += 4) {     // tail full quads
            int s = qsel(lane, __builtin_amdgcn_readlane(myidx, j),
                               __builtin_amdgcn_readlane(myidx, j + 1),
                               __builtin_amdgcn_readlane(myidx, j + 2),
                               __builtin_amdgcn_readlane(myidx, j + 3));
            uint4 u = Tb4[s * 16 + m];
            accum8(a, u);
        }
        if (j < cnt) {                     // 1..3 tail edges
            int rem = cnt - j;
            int s0 = __builtin_amdgcn_readlane(myidx, j);
            int s1 = __builtin_amdgcn_readlane(myidx, (j + 1 < cnt) ? j + 1 : j);
            int s2 = __builtin_amdgcn_readlane(myidx, (j + 2 < cnt) ? j + 2 : j);
            int s  = qsel(lane, s0, s1, s2, s0);
            if ((lane >> 4) < rem) {
                uint4 u = Tb4[s * 16 + m];
                accum8(a, u);
            }
        }
        if (ck + 1 < nchunk) {             // rare: degree > 64
            int c2 = p1 - (base + 64);
            myidx = (lane < c2) ? csr_src[base + 64 + lane] : 0;
        }
    }
}

// ---------------- init ----------------
__global__ void k_init(int* degi, float* pooled, float* counts) {
    int i = blockIdx.x * 256 + threadIdx.x;
    if (i < NPAD) degi[i] = 0;
    if (i < NUM_GRAPHS * DIM) pooled[i] = 0.0f;
    if (i < NUM_GRAPHS) counts[i] = 0.0f;
}

// ---------------- W -> Wt bf16 transpose (all 3 layers) ----------------
__global__ void k_prep(const float* __restrict__ W1, const float* __restrict__ W2,
                       const float* __restrict__ W3, ushort_t* __restrict__ Wt) {
    int i = blockIdx.x * 256 + threadIdx.x;
    int mat = i >> 14;
    int idx = i & 16383;
    const float* W = (mat == 0) ? W1 : (mat == 1) ? W2 : W3;
    int n = idx >> 7, k = idx & 127;
    Wt[mat * 16384 + n * 128 + k] = f2bf(W[k * 128 + n]);
}

// ---------------- degree histogram; atomic return = within-row rank ----------------
__global__ void k_count(const int* __restrict__ dst, int* degi, int* rank, int nedges) {
    int e = blockIdx.x * 256 + threadIdx.x;
    if (e < nedges) rank[e] = atomicAdd(&degi[dst[e]], 1);
}

// ---------------- scan ----------------
__global__ __launch_bounds__(256) void k_scan1(const int* __restrict__ degi,
                                               int* rowptr, int* bsum) {
    __shared__ int sh[256];
    int i = blockIdx.x * 256 + threadIdx.x;
    int v = degi[i];
    sh[threadIdx.x] = v;
    __syncthreads();
    for (int off = 1; off < 256; off <<= 1) {
        int t = (threadIdx.x >= off) ? sh[threadIdx.x - off] : 0;
        __syncthreads();
        sh[threadIdx.x] += t;
        __syncthreads();
    }
    rowptr[i] = sh[threadIdx.x] - v;
    if (threadIdx.x == 255) bsum[blockIdx.x] = sh[255];
}

__global__ __launch_bounds__(256) void k_scan2(int* bsum, int nblocks) {
    __shared__ int sh[256];
    int v = (threadIdx.x < nblocks) ? bsum[threadIdx.x] : 0;
    sh[threadIdx.x] = v;
    __syncthreads();
    for (int off = 1; off < 256; off <<= 1) {
        int t = (threadIdx.x >= off) ? sh[threadIdx.x - off] : 0;
        __syncthreads();
        sh[threadIdx.x] += t;
        __syncthreads();
    }
    if (threadIdx.x < nblocks) bsum[threadIdx.x] = sh[threadIdx.x] - v;
}

__global__ __launch_bounds__(256) void k_scan3(int* rowptr, const int* __restrict__ bsum,
                                               const int* __restrict__ degi,
                                               float* dinv) {
    int i = blockIdx.x * 256 + threadIdx.x;
    rowptr[i] = rowptr[i] + bsum[blockIdx.x];
    if (i < N_NODES) dinv[i] = rsqrtf((float)degi[i] + 1.0f);
}

// ---------------- CSR fill: atomic-free scatter via precomputed rank ----------------
__global__ void k_fill(const int* __restrict__ src, const int* __restrict__ dst,
                       const int* __restrict__ rank, const int* __restrict__ rowptr,
                       int* csr_src, int nedges) {
    int e = blockIdx.x * 256 + threadIdx.x;
    if (e < nedges) csr_src[rowptr[dst[e]] + rank[e]] = src[e];
}

// ---------------- layer-1 matmul: Tb1' = (x @ W1) * dinv[row] ----------------
__global__ __launch_bounds__(256) void k_mm1(
    const float* __restrict__ xin, const ushort_t* __restrict__ WtG,
    const float* __restrict__ dinv, ushort_t* __restrict__ TbOut)
{
    __shared__ ushort_t Wl[DIM * XPITCH];
    __shared__ ushort_t Xl[64 * XPITCH];

    const int tid = threadIdx.x;
    const int rowbase = blockIdx.x * 64;

    #pragma unroll
    for (int i = 0; i < 8; ++i) {
        int g = tid + i * 256;
        uint4 v = ((const uint4*)WtG)[g];
        *((uint4*)&Wl[(g >> 4) * XPITCH + (g & 15) * 8]) = v;
    }
    #pragma unroll
    for (int i = 0; i < 8; ++i) {
        int c = tid + i * 256;
        int row = c >> 5;
        int grow = rowbase + row;
        float4 f = make_float4(0.f, 0.f, 0.f, 0.f);
        if (grow < N_NODES)
            f = ((const float4*)xin)[(long long)rowbase * 32 + c];
        ushort4 h;
        h.x = f2bf(f.x); h.y = f2bf(f.y); h.z = f2bf(f.z); h.w = f2bf(f.w);
        *((ushort4*)&Xl[row * XPITCH + (c & 31) * 4]) = h;
    }
    __syncthreads();

    const int wave = tid >> 6;
    const int lane = tid & 63;
    const int quad = lane >> 4;
    const int lm   = lane & 15;
    const int m0   = wave * 16;

    short8 af[4];
    #pragma unroll
    for (int k0 = 0; k0 < 4; ++k0)
        af[k0] = *(const short8*)&Xl[(m0 + lm) * XPITCH + k0 * 32 + quad * 8];

    int noder[4]; float di[4]; bool okr[4];
    #pragma unroll
    for (int r = 0; r < 4; ++r) {
        noder[r] = rowbase + m0 + quad * 4 + r;
        okr[r] = (noder[r] < N_NODES);
        di[r] = okr[r] ? dinv[noder[r]] : 0.f;
    }

    for (int n0 = 0; n0 < DIM; n0 += 16) {
        f32x4 acc = {0.f, 0.f, 0.f, 0.f};
        #pragma unroll
        for (int k0 = 0; k0 < 4; ++k0) {
            short8 bf = *(const short8*)&Wl[(n0 + lm) * XPITCH + k0 * 32 + quad * 8];
            acc = __builtin_amdgcn_mfma_f32_16x16x32_bf16(af[k0], bf, acc, 0, 0, 0);
        }
        int n = n0 + lm;
        #pragma unroll
        for (int r = 0; r < 4; ++r)
            if (okr[r])
                TbOut[(long long)noder[r] * DIM + n] = f2bf(acc[r] * di[r]);
    }
}

// ---------------- fused: X = ReLU(b + dinv[n]*Sum Tb'[s]) ; Tb_out' = (X@W)*dinv ----------------
// Round-8 structure; gather core swapped to quad-lane (1 VMEM inst / 4 edges).
__global__ __launch_bounds__(256) void k_fused(
    const int* __restrict__ rowptr, const int* __restrict__ csr_src,
    const float* __restrict__ dinv, const uint_t* __restrict__ TbIn,
    const ushort_t* __restrict__ WtG, const float* __restrict__ b_prev,
    ushort_t* __restrict__ TbOut)
{
    __shared__ ushort_t Xl[16 * XPITCH];   // 4352 B

    const int tid = threadIdx.x;
    const int rowbase = blockIdx.x * 16;
    const int wave = tid >> 6;
    const int lane = tid & 63;
    const int m    = lane & 15;
    const uint4* Tb4 = (const uint4*)TbIn;

    float4 blo = ((const float4*)b_prev)[m * 2];
    float4 bhi = ((const float4*)b_prev)[m * 2 + 1];

    // rowptr for this wave's 4 nodes: one coalesced load + readlane
    const int nfirst = rowbase + wave * 4;
    int pv = (lane < 5) ? rowptr[nfirst + lane] : 0;
    int p[5];
    #pragma unroll
    for (int i = 0; i < 5; ++i) p[i] = __builtin_amdgcn_readlane(pv, i);

    // prefetch node 0's index vector
    int idx_n;
    {
        int d0 = p[1] - p[0];
        idx_n = (lane < d0) ? csr_src[p[0] + lane] : 0;
    }

    #pragma unroll
    for (int t = 0; t < 4; ++t) {
        int idx_cur = idx_n;
        if (t < 3) {                        // prefetch next node's indices
            int dn = p[t + 2] - p[t + 1];
            idx_n = (lane < dn) ? csr_src[p[t + 1] + lane] : 0;
        }
        int r = wave * 4 + t;
        int n = rowbase + r;
        float a[8] = {0.f, 0.f, 0.f, 0.f, 0.f, 0.f, 0.f, 0.f};
        float dd = 0.f;
        uint4 us = make_uint4(0u, 0u, 0u, 0u);
        if (n < N_NODES) {
            us = Tb4[n * 16 + m];           // self row (issues first)
            dd = dinv[n];
            quad_gather(lane, m, idx_cur, p[t], p[t + 1], csr_src, Tb4, a);
        }
        // merge quarter partials (whole wave; n is wave-uniform)
        #pragma unroll
        for (int i = 0; i < 8; ++i) {
            a[i] += __shfl_xor(a[i], 16);
            a[i] += __shfl_xor(a[i], 32);
        }
        accum8(a, us);                      // self counted once (post-merge)
        if (lane < 16) {
            short8 hh;
            hh[0] = (short)f2bf(fmaxf(blo.x + a[0] * dd, 0.f));
            hh[1] = (short)f2bf(fmaxf(blo.y + a[1] * dd, 0.f));
            hh[2] = (short)f2bf(fmaxf(blo.z + a[2] * dd, 0.f));
            hh[3] = (short)f2bf(fmaxf(blo.w + a[3] * dd, 0.f));
            hh[4] = (short)f2bf(fmaxf(bhi.x + a[4] * dd, 0.f));
            hh[5] = (short)f2bf(fmaxf(bhi.y + a[5] * dd, 0.f));
            hh[6] = (short)f2bf(fmaxf(bhi.z + a[6] * dd, 0.f));
            hh[7] = (short)f2bf(fmaxf(bhi.w + a[7] * dd, 0.f));
            *((short8*)&Xl[r * XPITCH + m * 8]) = hh;
        }
    }
    __syncthreads();

    const int quad = lane >> 4;
    const int lm   = lane & 15;

    short8 af[4];
    #pragma unroll
    for (int k0 = 0; k0 < 4; ++k0)
        af[k0] = *(const short8*)&Xl[lm * XPITCH + k0 * 32 + quad * 8];

    int noder[4]; float di[4]; bool okr[4];
    #pragma unroll
    for (int r = 0; r < 4; ++r) {
        noder[r] = rowbase + quad * 4 + r;
        okr[r] = (noder[r] < N_NODES);
        di[r] = okr[r] ? dinv[noder[r]] : 0.f;
    }

    #pragma unroll
    for (int hh = 0; hh < 2; ++hh) {
        int n0 = wave * 32 + hh * 16;
        f32x4 acc = {0.f, 0.f, 0.f, 0.f};
        #pragma unroll
        for (int k0 = 0; k0 < 4; ++k0) {
            short8 bf = *(const short8*)&WtG[(n0 + lm) * DIM + k0 * 32 + quad * 8];
            acc = __builtin_amdgcn_mfma_f32_16x16x32_bf16(af[k0], bf, acc, 0, 0, 0);
        }
        int n = n0 + lm;
        #pragma unroll
        for (int r = 0; r < 4; ++r)
            if (okr[r])
                TbOut[(long long)noder[r] * DIM + n] = f2bf(acc[r] * di[r]);
    }
}

// ---------------- fused gather + mean-pool, LDS flush accumulation ----------------
// Round-8 8-row strips; quad-lane gather core + idx prefetch across nodes.
// Lane owns channels ch = 8m+2q, ch+1 for the run accumulator / flushes.
__global__ __launch_bounds__(256) void k_poolgather(
    const int* __restrict__ rowptr, const int* __restrict__ csr_src,
    const float* __restrict__ dinv, const uint_t* __restrict__ Tb,
    const float* __restrict__ b3, const int* __restrict__ batch,
    float* pooled, float* counts)
{
    __shared__ float lp[8][DIM];   // 4 KB
    __shared__ float lc[8];

    const int tid  = threadIdx.x;
    const int wave = tid >> 6;
    const int lane = tid & 63;
    const int m    = lane & 15;
    const int q    = lane >> 4;
    const int blk0 = blockIdx.x * 32;
    const uint4* Tb4 = (const uint4*)Tb;
    const int ch = 8 * m + 2 * q;

    #pragma unroll
    for (int i = 0; i < 4; ++i) ((float*)lp)[tid + i * 256] = 0.f;
    if (tid < 8) lc[tid] = 0.f;
    __syncthreads();

    const int gbase = batch[min(blk0, N_NODES - 1)];
    int n0 = blk0 + wave * 8;

    if (n0 < N_NODES) {
        int nend = min(n0 + 8, N_NODES);
        float bb0 = b3[ch], bb1 = b3[ch + 1];

        int pv = (lane < 9) ? rowptr[min(n0 + lane, NPAD)] : 0;
        int p[9];
        #pragma unroll
        for (int i = 0; i < 9; ++i) p[i] = __builtin_amdgcn_readlane(pv, i);

        int cur = batch[n0];
        int runstart = n0;
        float2 pacc = make_float2(0.f, 0.f);

        int idx_n;
        {
            int d0 = p[1] - p[0];
            idx_n = (lane < d0) ? csr_src[p[0] + lane] : 0;
        }

        for (int i = 0; i < nend - n0; ++i) {
            int n = n0 + i;
            int idx_cur = idx_n;
            if (i < 7) {
                int dn = p[i + 2] - p[i + 1];
                idx_n = (lane < dn) ? csr_src[p[i + 1] + lane] : 0;
            }
            int g = batch[n];
            if (g != cur) {
                int slot = cur - gbase;
                if (slot < 8) {
                    atomicAdd(&lp[slot][ch], pacc.x);
                    atomicAdd(&lp[slot][ch + 1], pacc.y);
                    if (lane == 0) atomicAdd(&lc[slot], (float)(n - runstart));
                } else {
                    atomicAdd(&pooled[cur * DIM + ch], pacc.x);
                    atomicAdd(&pooled[cur * DIM + ch + 1], pacc.y);
                    if (lane == 0) atomicAdd(&counts[cur], (float)(n - runstart));
                }
                pacc.x = 0.f; pacc.y = 0.f; cur = g; runstart = n;
            }
            float a[8] = {0.f, 0.f, 0.f, 0.f, 0.f, 0.f, 0.f, 0.f};
            uint4 us = Tb4[n * 16 + m];
            quad_gather(lane, m, idx_cur, p[i], p[i + 1], csr_src, Tb4, a);
            #pragma unroll
            for (int k = 0; k < 8; ++k) {
                a[k] += __shfl_xor(a[k], 16);
                a[k] += __shfl_xor(a[k], 32);
            }
            accum8(a, us);
            float x0 = (q == 0) ? a[0] : (q == 1) ? a[2] : (q == 2) ? a[4] : a[6];
            float x1 = (q == 0) ? a[1] : (q == 1) ? a[3] : (q == 2) ? a[5] : a[7];
            float dd = dinv[n];
            pacc.x += bb0 + x0 * dd;
            pacc.y += bb1 + x1 * dd;
        }
        int slot = cur - gbase;
        if (slot < 8) {
            atomicAdd(&lp[slot][ch], pacc.x);
            atomicAdd(&lp[slot][ch + 1], pacc.y);
            if (lane == 0) atomicAdd(&lc[slot], (float)(nend - runstart));
        } else {
            atomicAdd(&pooled[cur * DIM + ch], pacc.x);
            atomicAdd(&pooled[cur * DIM + ch + 1], pacc.y);
            if (lane == 0) atomicAdd(&counts[cur], (float)(nend - runstart));
        }
    }
    __syncthreads();

    #pragma unroll
    for (int s = 0; s < 8; ++s) {
        if (lc[s] != 0.f) {
            if (tid < DIM) atomicAdd(&pooled[(gbase + s) * DIM + tid], lp[s][tid]);
            if (tid == DIM) atomicAdd(&counts[gbase + s], lc[s]);
        }
    }
}

// ---------------- classifier head ----------------
__global__ __launch_bounds__(128) void k_cls(
    const float* __restrict__ pooled, const float* __restrict__ counts,
    const float* __restrict__ C1, const float* __restrict__ bc1,
    const float* __restrict__ C2, const float* __restrict__ bc2,
    float* out)
{
    __shared__ float pm[DIM];
    __shared__ float gv[DIM];
    int g = blockIdx.x, j = threadIdx.x;
    float cnt = fmaxf(counts[g], 1.0f);
    pm[j] = pooled[g * DIM + j] / cnt;
    __syncthreads();
    float a = bc1[j];
    for (int k = 0; k < DIM; ++k) a += pm[k] * C1[k * DIM + j];
    gv[j] = fmaxf(a, 0.f);
    __syncthreads();
    if (j < NUM_CLASSES) {
        float o = bc2[j];
        for (int k = 0; k < DIM; ++k) o += gv[k] * C2[k * NUM_CLASSES + j];
        out[g * NUM_CLASSES + j] = o;
    }
}

extern "C" void kernel_launch(void* const* d_in, const int* in_sizes, int n_in,
                              void* d_out, int out_size, void* d_ws, size_t ws_size,
                              hipStream_t stream) {
    const float* x    = (const float*)d_in[0];
    const int*   ei   = (const int*)d_in[1];
    const int*   batch= (const int*)d_in[2];
    const float* W1   = (const float*)d_in[3];
    const float* b1   = (const float*)d_in[4];
    const float* W2   = (const float*)d_in[5];
    const float* b2   = (const float*)d_in[6];
    const float* W3   = (const float*)d_in[7];
    const float* b3   = (const float*)d_in[8];
    const float* C1   = (const float*)d_in[9];
    const float* bc1  = (const float*)d_in[10];
    const float* C2   = (const float*)d_in[11];
    const float* bc2  = (const float*)d_in[12];

    const int nedges = in_sizes[1] / 2;
    const int* src = ei;
    const int* dst = ei + nedges;

    // workspace layout (4-byte units)
    float*    dinv    = (float*)d_ws;                           // NPAD
    uint_t*   TbA     = (uint_t*)(dinv + NPAD);                 // N_NODES*64
    uint_t*   TbB     = TbA + (long long)N_NODES * 64;          // N_NODES*64
    float*    pooled  = (float*)(TbB + (long long)N_NODES * 64);// 8192
    float*    counts  = pooled + NUM_GRAPHS * DIM;              // 64
    int*      degi    = (int*)(counts + 64);                    // NPAD
    int*      rowptr  = degi + NPAD;                            // NPAD+256
    int*      bsum    = rowptr + NPAD + 256;                    // 256
    int*      rank    = bsum + 256;                             // nedges
    int*      csr_src = rank + nedges;                          // nedges
    ushort_t* Wt      = (ushort_t*)(csr_src + nedges);          // 3*16384 bf16

    const int nodeBlocks = NPAD / 256;                     // 196
    const int mmBlocks   = (N_NODES + 63) / 64;            // 782
    const int fusedBlocks= (N_NODES + 15) / 16;            // 3125
    const int pgBlocks   = (N_NODES + 31) / 32;            // 1563
    const int edgeBlocks = (nedges + 255) / 256;           // 3125

    k_init<<<nodeBlocks, 256, 0, stream>>>(degi, pooled, counts);
    k_prep<<<192, 256, 0, stream>>>(W1, W2, W3, Wt);
    k_count<<<edgeBlocks, 256, 0, stream>>>(dst, degi, rank, nedges);
    k_scan1<<<nodeBlocks, 256, 0, stream>>>(degi, rowptr, bsum);
    k_scan2<<<1, 256, 0, stream>>>(bsum, nodeBlocks);
    k_scan3<<<nodeBlocks, 256, 0, stream>>>(rowptr, bsum, degi, dinv);
    k_fill<<<edgeBlocks, 256, 0, stream>>>(src, dst, rank, rowptr, csr_src, nedges);

    k_mm1<<<mmBlocks, 256, 0, stream>>>(x, Wt, dinv, (ushort_t*)TbA);
    k_fused<<<fusedBlocks, 256, 0, stream>>>(rowptr, csr_src, dinv, TbA,
                                             Wt + 16384, b1, (ushort_t*)TbB);
    k_fused<<<fusedBlocks, 256, 0, stream>>>(rowptr, csr_src, dinv, TbB,
                                             Wt + 32768, b2, (ushort_t*)TbA);
    k_poolgather<<<pgBlocks, 256, 0, stream>>>(rowptr, csr_src, dinv, TbA,
                                               b3, batch, pooled, counts);
    k_cls<<<NUM_GRAPHS, 128, 0, stream>>>(pooled, counts, C1, bc1, C2, bc2,
                                          (float*)d_out);
}

// Round 10
// 284.862 us; speedup vs baseline: 1.4161x; 1.0027x over previous
//
#include <hip/hip_runtime.h>
#include <hip/hip_bf16.h>

#define N_NODES    50000
#define DIM        128
#define NUM_GRAPHS 64
#define NUM_CLASSES 3
#define NPAD       50176   // 196*256
#define XPITCH     136     // LDS row pitch in ushorts (17 x 16B, odd -> conflict-free b128)
#define MMB        782     // (N_NODES+63)/64

typedef unsigned short ushort_t;
typedef unsigned int   uint_t;
typedef __attribute__((ext_vector_type(8))) short short8;
typedef __attribute__((ext_vector_type(4))) float f32x4;

__device__ __forceinline__ ushort_t f2bf(float f) {
    union { float f; uint_t u; } v; v.f = f;
    uint_t r = v.u + 0x7fffu + ((v.u >> 16) & 1u);   // RNE
    return (ushort_t)(r >> 16);
}
__device__ __forceinline__ float bflo(uint_t u) {
    union { uint_t u; float f; } v; v.u = u << 16; return v.f;
}
__device__ __forceinline__ float bfhi(uint_t u) {
    union { uint_t u; float f; } v; v.u = u & 0xffff0000u; return v.f;
}
__device__ __forceinline__ float rlf(float v, int l) {
    union { float f; int i; } c; c.f = v;
    union { int i; float f; } d; d.i = __builtin_amdgcn_readlane(c.i, l);
    return d.f;
}

// a[i] += w * row_val[i]  (static idx only)
__device__ __forceinline__ void wfma8(float* a, uint4 u, float w) {
    a[0] += w * bflo(u.x); a[1] += w * bfhi(u.x);
    a[2] += w * bflo(u.y); a[3] += w * bfhi(u.y);
    a[4] += w * bflo(u.z); a[5] += w * bfhi(u.z);
    a[6] += w * bflo(u.w); a[7] += w * bfhi(u.w);
}

// pick this quarter-wave's value from 4 wave-uniform scalars (3 cndmask)
__device__ __forceinline__ int qsel(int lane, int s0, int s1, int s2, int s3) {
    int lo = (lane & 16) ? s1 : s0;
    int hi = (lane & 16) ? s3 : s2;
    return (lane & 32) ? hi : lo;
}
__device__ __forceinline__ float qself(int lane, float s0, float s1, float s2, float s3) {
    float lo = (lane & 16) ? s1 : s0;
    float hi = (lane & 16) ? s3 : s2;
    return (lane & 32) ? hi : lo;
}

// Quad-lane readlane-fed WEIGHTED gather: quarter q = lane>>4 takes edge 4k+q;
// lane m = lane&15 holds channels 8m..8m+7 as one dwordx4. One VMEM inst = 4
// edges (round-9 proven). NEW: rows are UNSCALED; per-edge weight w = dinv[src]
// rides the same readlane/qsel path (myw = dinv[myidx], loaded per node by the
// caller, prefetch-hidden). accum becomes FMA -- same rounding count as before.
// Caller must shfl_xor(16,32)-reduce quarter partials + add dd-weighted self.
__device__ __forceinline__ void quad_gather_w(
    int lane, int m, int myidx0, float myw0, int p0, int p1,
    const int* __restrict__ csr_src, const float* __restrict__ dinv,
    const uint4* __restrict__ Tb4, float* a)
{
    int deg = p1 - p0;
    if (deg < 0) deg = 0;
    int nchunk = (deg + 63) >> 6;
    int myidx = myidx0; float myw = myw0;
    for (int ck = 0; ck < nchunk; ++ck) {
        int base = p0 + (ck << 6);
        int cnt = p1 - base; if (cnt > 64) cnt = 64;
        int nb = cnt >> 3;                 // 8-edge batches = 2 quad-loads
        if (nb > 0) {
            uint4 u0, u1; float w0, w1;
            {
                int s = qsel(lane, __builtin_amdgcn_readlane(myidx, 0),
                                   __builtin_amdgcn_readlane(myidx, 1),
                                   __builtin_amdgcn_readlane(myidx, 2),
                                   __builtin_amdgcn_readlane(myidx, 3));
                w0 = qself(lane, rlf(myw, 0), rlf(myw, 1), rlf(myw, 2), rlf(myw, 3));
                u0 = Tb4[s * 16 + m];
                s = qsel(lane, __builtin_amdgcn_readlane(myidx, 4),
                               __builtin_amdgcn_readlane(myidx, 5),
                               __builtin_amdgcn_readlane(myidx, 6),
                               __builtin_amdgcn_readlane(myidx, 7));
                w1 = qself(lane, rlf(myw, 4), rlf(myw, 5), rlf(myw, 6), rlf(myw, 7));
                u1 = Tb4[s * 16 + m];
            }
            for (int b = 1; b < nb; ++b) {
                int jb = b * 8;
                int s = qsel(lane, __builtin_amdgcn_readlane(myidx, jb),
                                   __builtin_amdgcn_readlane(myidx, jb + 1),
                                   __builtin_amdgcn_readlane(myidx, jb + 2),
                                   __builtin_amdgcn_readlane(myidx, jb + 3));
                float nw0 = qself(lane, rlf(myw, jb), rlf(myw, jb + 1),
                                        rlf(myw, jb + 2), rlf(myw, jb + 3));
                uint4 n0v = Tb4[s * 16 + m];
                s = qsel(lane, __builtin_amdgcn_readlane(myidx, jb + 4),
                               __builtin_amdgcn_readlane(myidx, jb + 5),
                               __builtin_amdgcn_readlane(myidx, jb + 6),
                               __builtin_amdgcn_readlane(myidx, jb + 7));
                float nw1 = qself(lane, rlf(myw, jb + 4), rlf(myw, jb + 5),
                                        rlf(myw, jb + 6), rlf(myw, jb + 7));
                uint4 n1v = Tb4[s * 16 + m];
                wfma8(a, u0, w0); wfma8(a, u1, w1);
                u0 = n0v; u1 = n1v; w0 = nw0; w1 = nw1;
            }
            wfma8(a, u0, w0); wfma8(a, u1, w1);
        }
        int j = nb * 8;
        for (; j + 4 <= cnt; j += 4) {     // tail full quads
            int s = qsel(lane, __builtin_amdgcn_readlane(myidx, j),
                               __builtin_amdgcn_readlane(myidx, j + 1),
                               __builtin_amdgcn_readlane(myidx, j + 2),
                               __builtin_amdgcn_readlane(myidx, j + 3));
            float w = qself(lane, rlf(myw, j), rlf(myw, j + 1),
                                  rlf(myw, j + 2), rlf(myw, j + 3));
            uint4 u = Tb4[s * 16 + m];
            wfma8(a, u, w);
        }
        if (j < cnt) {                     // 1..3 tail edges
            int rem = cnt - j;
            int j1 = (j + 1 < cnt) ? j + 1 : j;
            int j2 = (j + 2 < cnt) ? j + 2 : j;
            int s = qsel(lane, __builtin_amdgcn_readlane(myidx, j),
                               __builtin_amdgcn_readlane(myidx, j1),
                               __builtin_amdgcn_readlane(myidx, j2),
                               __builtin_amdgcn_readlane(myidx, j));
            float w = qself(lane, rlf(myw, j), rlf(myw, j1), rlf(myw, j2), rlf(myw, j));
            if ((lane >> 4) < rem) {
                uint4 u = Tb4[s * 16 + m];
                wfma8(a, u, w);
            }
        }
        if (ck + 1 < nchunk) {             // rare: degree > 64
            int c2 = p1 - (base + 64);
            myidx = (lane < c2) ? csr_src[base + 64 + lane] : 0;
            myw = dinv[myidx];
        }
    }
}

// ---------------- init + W->Wt prep (merged) ----------------
__global__ void k_initprep(int* degi, float* pooled, float* counts,
                           const float* __restrict__ W1, const float* __restrict__ W2,
                           const float* __restrict__ W3, ushort_t* __restrict__ Wt) {
    int i = blockIdx.x * 256 + threadIdx.x;
    if (i < NPAD) degi[i] = 0;
    if (i < NUM_GRAPHS * DIM) pooled[i] = 0.0f;
    if (i < NUM_GRAPHS) counts[i] = 0.0f;
    if (i < 3 * 16384) {
        int mat = i >> 14;
        int idx = i & 16383;
        const float* W = (mat == 0) ? W1 : (mat == 1) ? W2 : W3;
        int n = idx >> 7, k = idx & 127;
        Wt[mat * 16384 + n * 128 + k] = f2bf(W[k * 128 + n]);
    }
}

// ---------------- scan ----------------
__global__ __launch_bounds__(256) void k_scan1(const int* __restrict__ degi,
                                               int* rowptr, int* bsum) {
    __shared__ int sh[256];
    int i = blockIdx.x * 256 + threadIdx.x;
    int v = degi[i];
    sh[threadIdx.x] = v;
    __syncthreads();
    for (int off = 1; off < 256; off <<= 1) {
        int t = (threadIdx.x >= off) ? sh[threadIdx.x - off] : 0;
        __syncthreads();
        sh[threadIdx.x] += t;
        __syncthreads();
    }
    rowptr[i] = sh[threadIdx.x] - v;
    if (threadIdx.x == 255) bsum[blockIdx.x] = sh[255];
}

__global__ __launch_bounds__(256) void k_scan2(int* bsum, int nblocks) {
    __shared__ int sh[256];
    int v = (threadIdx.x < nblocks) ? bsum[threadIdx.x] : 0;
    sh[threadIdx.x] = v;
    __syncthreads();
    for (int off = 1; off < 256; off <<= 1) {
        int t = (threadIdx.x >= off) ? sh[threadIdx.x - off] : 0;
        __syncthreads();
        sh[threadIdx.x] += t;
        __syncthreads();
    }
    if (threadIdx.x < nblocks) bsum[threadIdx.x] = sh[threadIdx.x] - v;
}

// dinv written for ALL of NPAD (padding -> 1.0) so hoisted float4 reads are safe
__global__ __launch_bounds__(256) void k_scan3(int* rowptr, const int* __restrict__ bsum,
                                               const int* __restrict__ degi,
                                               float* dinv) {
    int i = blockIdx.x * 256 + threadIdx.x;
    rowptr[i] = rowptr[i] + bsum[blockIdx.x];
    dinv[i] = rsqrtf((float)degi[i] + 1.0f);
}

// ---------------- CSR fill: atomic-free scatter via precomputed rank ----------------
__global__ void k_fill(const int* __restrict__ src, const int* __restrict__ dst,
                       const int* __restrict__ rank, const int* __restrict__ rowptr,
                       int* csr_src, int nedges) {
    int e = blockIdx.x * 256 + threadIdx.x;
    if (e < nedges) csr_src[rowptr[dst[e]] + rank[e]] = src[e];
}

// ---------------- merged: layer-1 matmul (UNSCALED) + degree count ----------------
// mm1 no longer needs dinv (scaling moved into the weighted gather), so it is
// independent of the count->scan chain -> run count concurrently via grid split.
__global__ __launch_bounds__(256) void k_mm1c(
    const float* __restrict__ xin, const ushort_t* __restrict__ WtG,
    ushort_t* __restrict__ TbOut,
    const int* __restrict__ dst, int* degi, int* rank, int nedges)
{
    __shared__ ushort_t Wl[DIM * XPITCH];
    __shared__ ushort_t Xl[64 * XPITCH];

    if ((int)blockIdx.x >= MMB) {          // count part (block-uniform branch)
        int e = ((int)blockIdx.x - MMB) * 256 + threadIdx.x;
        if (e < nedges) rank[e] = atomicAdd(&degi[dst[e]], 1);
        return;
    }

    const int tid = threadIdx.x;
    const int rowbase = blockIdx.x * 64;

    #pragma unroll
    for (int i = 0; i < 8; ++i) {
        int g = tid + i * 256;
        uint4 v = ((const uint4*)WtG)[g];
        *((uint4*)&Wl[(g >> 4) * XPITCH + (g & 15) * 8]) = v;
    }
    #pragma unroll
    for (int i = 0; i < 8; ++i) {
        int c = tid + i * 256;
        int row = c >> 5;
        int grow = rowbase + row;
        float4 f = make_float4(0.f, 0.f, 0.f, 0.f);
        if (grow < N_NODES)
            f = ((const float4*)xin)[(long long)rowbase * 32 + c];
        ushort4 h;
        h.x = f2bf(f.x); h.y = f2bf(f.y); h.z = f2bf(f.z); h.w = f2bf(f.w);
        *((ushort4*)&Xl[row * XPITCH + (c & 31) * 4]) = h;
    }
    __syncthreads();

    const int wave = tid >> 6;
    const int lane = tid & 63;
    const int quad = lane >> 4;
    const int lm   = lane & 15;
    const int m0   = wave * 16;

    short8 af[4];
    #pragma unroll
    for (int k0 = 0; k0 < 4; ++k0)
        af[k0] = *(const short8*)&Xl[(m0 + lm) * XPITCH + k0 * 32 + quad * 8];

    int noder[4]; bool okr[4];
    #pragma unroll
    for (int r = 0; r < 4; ++r) {
        noder[r] = rowbase + m0 + quad * 4 + r;
        okr[r] = (noder[r] < N_NODES);
    }

    for (int n0 = 0; n0 < DIM; n0 += 16) {
        f32x4 acc = {0.f, 0.f, 0.f, 0.f};
        #pragma unroll
        for (int k0 = 0; k0 < 4; ++k0) {
            short8 bf = *(const short8*)&Wl[(n0 + lm) * XPITCH + k0 * 32 + quad * 8];
            acc = __builtin_amdgcn_mfma_f32_16x16x32_bf16(af[k0], bf, acc, 0, 0, 0);
        }
        int n = n0 + lm;
        #pragma unroll
        for (int r = 0; r < 4; ++r)
            if (okr[r])
                TbOut[(long long)noder[r] * DIM + n] = f2bf(acc[r]);
    }
}

// ---------------- fused: X = ReLU(b + dd*(Sum w_s*y_s + dd*y_n)) ; Tb_out = X@W ----------------
__global__ __launch_bounds__(256) void k_fused(
    const int* __restrict__ rowptr, const int* __restrict__ csr_src,
    const float* __restrict__ dinv, const uint_t* __restrict__ TbIn,
    const ushort_t* __restrict__ WtG, const float* __restrict__ b_prev,
    ushort_t* __restrict__ TbOut)
{
    __shared__ ushort_t Xl[16 * XPITCH];   // 4352 B

    const int tid = threadIdx.x;
    const int rowbase = blockIdx.x * 16;
    const int wave = tid >> 6;
    const int lane = tid & 63;
    const int m    = lane & 15;
    const uint4* Tb4 = (const uint4*)TbIn;

    float4 blo = ((const float4*)b_prev)[m * 2];
    float4 bhi = ((const float4*)b_prev)[m * 2 + 1];

    // rowptr for this wave's 4 nodes: one coalesced load + readlane
    const int nfirst = rowbase + wave * 4;
    int pv = (lane < 5) ? rowptr[nfirst + lane] : 0;
    int p[5];
    #pragma unroll
    for (int i = 0; i < 5; ++i) p[i] = __builtin_amdgcn_readlane(pv, i);

    const float4 dv = *(const float4*)&dinv[nfirst];   // nfirst%4==0; NPAD padded

    // prefetch node 0's index + weight vectors
    int idx_n; float w_n;
    {
        int d0 = p[1] - p[0];
        idx_n = (lane < d0) ? csr_src[p[0] + lane] : 0;
    }
    w_n = dinv[idx_n];

    #pragma unroll
    for (int t = 0; t < 4; ++t) {
        int idx_cur = idx_n; float w_cur = w_n;
        if (t < 3) {                        // prefetch next node's indices (early)
            int dn = p[t + 2] - p[t + 1];
            idx_n = (lane < dn) ? csr_src[p[t + 1] + lane] : 0;
        }
        int r = wave * 4 + t;
        int n = rowbase + r;
        float dd = (t == 0) ? dv.x : (t == 1) ? dv.y : (t == 2) ? dv.z : dv.w;
        float a[8] = {0.f, 0.f, 0.f, 0.f, 0.f, 0.f, 0.f, 0.f};
        uint4 us = make_uint4(0u, 0u, 0u, 0u);
        if (n < N_NODES) {
            us = Tb4[n * 16 + m];           // self row (issues first)
            quad_gather_w(lane, m, idx_cur, w_cur, p[t], p[t + 1],
                          csr_src, dinv, Tb4, a);
        }
        if (t < 3) w_n = dinv[idx_n];       // weight prefetch (late: idx returned)
        // merge quarter partials (whole wave; n is wave-uniform)
        #pragma unroll
        for (int i = 0; i < 8; ++i) {
            a[i] += __shfl_xor(a[i], 16);
            a[i] += __shfl_xor(a[i], 32);
        }
        wfma8(a, us, dd);                   // self with weight dinv[n]
        if (lane < 16) {
            short8 hh;
            hh[0] = (short)f2bf(fmaxf(blo.x + a[0] * dd, 0.f));
            hh[1] = (short)f2bf(fmaxf(blo.y + a[1] * dd, 0.f));
            hh[2] = (short)f2bf(fmaxf(blo.z + a[2] * dd, 0.f));
            hh[3] = (short)f2bf(fmaxf(blo.w + a[3] * dd, 0.f));
            hh[4] = (short)f2bf(fmaxf(bhi.x + a[4] * dd, 0.f));
            hh[5] = (short)f2bf(fmaxf(bhi.y + a[5] * dd, 0.f));
            hh[6] = (short)f2bf(fmaxf(bhi.z + a[6] * dd, 0.f));
            hh[7] = (short)f2bf(fmaxf(bhi.w + a[7] * dd, 0.f));
            *((short8*)&Xl[r * XPITCH + m * 8]) = hh;
        }
    }
    __syncthreads();

    const int quad = lane >> 4;
    const int lm   = lane & 15;

    short8 af[4];
    #pragma unroll
    for (int k0 = 0; k0 < 4; ++k0)
        af[k0] = *(const short8*)&Xl[lm * XPITCH + k0 * 32 + quad * 8];

    int noder[4]; bool okr[4];
    #pragma unroll
    for (int r = 0; r < 4; ++r) {
        noder[r] = rowbase + quad * 4 + r;
        okr[r] = (noder[r] < N_NODES);
    }

    #pragma unroll
    for (int hh = 0; hh < 2; ++hh) {
        int n0 = wave * 32 + hh * 16;
        f32x4 acc = {0.f, 0.f, 0.f, 0.f};
        #pragma unroll
        for (int k0 = 0; k0 < 4; ++k0) {
            short8 bf = *(const short8*)&WtG[(n0 + lm) * DIM + k0 * 32 + quad * 8];
            acc = __builtin_amdgcn_mfma_f32_16x16x32_bf16(af[k0], bf, acc, 0, 0, 0);
        }
        int n = n0 + lm;
        #pragma unroll
        for (int r = 0; r < 4; ++r)
            if (okr[r])
                TbOut[(long long)noder[r] * DIM + n] = f2bf(acc[r]);   // unscaled
    }
}

// ---------------- fused weighted gather + mean-pool, LDS flush accumulation ----------------
__global__ __launch_bounds__(256) void k_poolgather(
    const int* __restrict__ rowptr, const int* __restrict__ csr_src,
    const float* __restrict__ dinv, const uint_t* __restrict__ Tb,
    const float* __restrict__ b3, const int* __restrict__ batch,
    float* pooled, float* counts)
{
    __shared__ float lp[8][DIM];   // 4 KB
    __shared__ float lc[8];

    const int tid  = threadIdx.x;
    const int wave = tid >> 6;
    const int lane = tid & 63;
    const int m    = lane & 15;
    const int q    = lane >> 4;
    const int blk0 = blockIdx.x * 32;
    const uint4* Tb4 = (const uint4*)Tb;
    const int ch = 8 * m + 2 * q;

    #pragma unroll
    for (int i = 0; i < 4; ++i) ((float*)lp)[tid + i * 256] = 0.f;
    if (tid < 8) lc[tid] = 0.f;
    __syncthreads();

    const int gbase = batch[min(blk0, N_NODES - 1)];
    int n0 = blk0 + wave * 8;

    if (n0 < N_NODES) {
        int nend = min(n0 + 8, N_NODES);
        float bb0 = b3[ch], bb1 = b3[ch + 1];

        int pv = (lane < 9) ? rowptr[min(n0 + lane, NPAD)] : 0;
        int p[9];
        #pragma unroll
        for (int i = 0; i < 9; ++i) p[i] = __builtin_amdgcn_readlane(pv, i);

        int cur = batch[n0];
        int runstart = n0;
        float2 pacc = make_float2(0.f, 0.f);

        int idx_n; float w_n;
        {
            int d0 = p[1] - p[0];
            idx_n = (lane < d0) ? csr_src[p[0] + lane] : 0;
        }
        w_n = dinv[idx_n];

        for (int i = 0; i < nend - n0; ++i) {
            int n = n0 + i;
            int idx_cur = idx_n; float w_cur = w_n;
            if (i < 7) {
                int dn = p[i + 2] - p[i + 1];
                idx_n = (lane < dn) ? csr_src[p[i + 1] + lane] : 0;
            }
            int g = batch[n];
            if (g != cur) {
                int slot = cur - gbase;
                if (slot < 8) {
                    atomicAdd(&lp[slot][ch], pacc.x);
                    atomicAdd(&lp[slot][ch + 1], pacc.y);
                    if (lane == 0) atomicAdd(&lc[slot], (float)(n - runstart));
                } else {
                    atomicAdd(&pooled[cur * DIM + ch], pacc.x);
                    atomicAdd(&pooled[cur * DIM + ch + 1], pacc.y);
                    if (lane == 0) atomicAdd(&counts[cur], (float)(n - runstart));
                }
                pacc.x = 0.f; pacc.y = 0.f; cur = g; runstart = n;
            }
            float a[8] = {0.f, 0.f, 0.f, 0.f, 0.f, 0.f, 0.f, 0.f};
            uint4 us = Tb4[n * 16 + m];
            quad_gather_w(lane, m, idx_cur, w_cur, p[i], p[i + 1],
                          csr_src, dinv, Tb4, a);
            if (i < 7) w_n = dinv[idx_n];   // weight prefetch (late)
            #pragma unroll
            for (int k = 0; k < 8; ++k) {
                a[k] += __shfl_xor(a[k], 16);
                a[k] += __shfl_xor(a[k], 32);
            }
            float dd = dinv[n];
            wfma8(a, us, dd);
            float x0 = (q == 0) ? a[0] : (q == 1) ? a[2] : (q == 2) ? a[4] : a[6];
            float x1 = (q == 0) ? a[1] : (q == 1) ? a[3] : (q == 2) ? a[5] : a[7];
            pacc.x += bb0 + x0 * dd;
            pacc.y += bb1 + x1 * dd;
        }
        int slot = cur - gbase;
        if (slot < 8) {
            atomicAdd(&lp[slot][ch], pacc.x);
            atomicAdd(&lp[slot][ch + 1], pacc.y);
            if (lane == 0) atomicAdd(&lc[slot], (float)(nend - runstart));
        } else {
            atomicAdd(&pooled[cur * DIM + ch], pacc.x);
            atomicAdd(&pooled[cur * DIM + ch + 1], pacc.y);
            if (lane == 0) atomicAdd(&counts[cur], (float)(nend - runstart));
        }
    }
    __syncthreads();

    #pragma unroll
    for (int s = 0; s < 8; ++s) {
        if (lc[s] != 0.f) {
            if (tid < DIM) atomicAdd(&pooled[(gbase + s) * DIM + tid], lp[s][tid]);
            if (tid == DIM) atomicAdd(&counts[gbase + s], lc[s]);
        }
    }
}

// ---------------- classifier head ----------------
__global__ __launch_bounds__(128) void k_cls(
    const float* __restrict__ pooled, const float* __restrict__ counts,
    const float* __restrict__ C1, const float* __restrict__ bc1,
    const float* __restrict__ C2, const float* __restrict__ bc2,
    float* out)
{
    __shared__ float pm[DIM];
    __shared__ float gv[DIM];
    int g = blockIdx.x, j = threadIdx.x;
    float cnt = fmaxf(counts[g], 1.0f);
    pm[j] = pooled[g * DIM + j] / cnt;
    __syncthreads();
    float a = bc1[j];
    for (int k = 0; k < DIM; ++k) a += pm[k] * C1[k * DIM + j];
    gv[j] = fmaxf(a, 0.f);
    __syncthreads();
    if (j < NUM_CLASSES) {
        float o = bc2[j];
        for (int k = 0; k < DIM; ++k) o += gv[k] * C2[k * NUM_CLASSES + j];
        out[g * NUM_CLASSES + j] = o;
    }
}

extern "C" void kernel_launch(void* const* d_in, const int* in_sizes, int n_in,
                              void* d_out, int out_size, void* d_ws, size_t ws_size,
                              hipStream_t stream) {
    const float* x    = (const float*)d_in[0];
    const int*   ei   = (const int*)d_in[1];
    const int*   batch= (const int*)d_in[2];
    const float* W1   = (const float*)d_in[3];
    const float* b1   = (const float*)d_in[4];
    const float* W2   = (const float*)d_in[5];
    const float* b2   = (const float*)d_in[6];
    const float* W3   = (const float*)d_in[7];
    const float* b3   = (const float*)d_in[8];
    const float* C1   = (const float*)d_in[9];
    const float* bc1  = (const float*)d_in[10];
    const float* C2   = (const float*)d_in[11];
    const float* bc2  = (const float*)d_in[12];

    const int nedges = in_sizes[1] / 2;
    const int* src = ei;
    const int* dst = ei + nedges;

    // workspace layout (4-byte units)
    float*    dinv    = (float*)d_ws;                           // NPAD
    uint_t*   TbA     = (uint_t*)(dinv + NPAD);                 // N_NODES*64
    uint_t*   TbB     = TbA + (long long)N_NODES * 64;          // N_NODES*64
    float*    pooled  = (float*)(TbB + (long long)N_NODES * 64);// 8192
    float*    counts  = pooled + NUM_GRAPHS * DIM;              // 64
    int*      degi    = (int*)(counts + 64);                    // NPAD
    int*      rowptr  = degi + NPAD;                            // NPAD+256
    int*      bsum    = rowptr + NPAD + 256;                    // 256
    int*      rank    = bsum + 256;                             // nedges
    int*      csr_src = rank + nedges;                          // nedges
    ushort_t* Wt      = (ushort_t*)(csr_src + nedges);          // 3*16384 bf16

    const int nodeBlocks = NPAD / 256;                     // 196
    const int fusedBlocks= (N_NODES + 15) / 16;            // 3125
    const int pgBlocks   = (N_NODES + 31) / 32;            // 1563
    const int edgeBlocks = (nedges + 255) / 256;           // 3125

    k_initprep<<<nodeBlocks, 256, 0, stream>>>(degi, pooled, counts, W1, W2, W3, Wt);
    k_mm1c<<<MMB + edgeBlocks, 256, 0, stream>>>(x, Wt, (ushort_t*)TbA,
                                                 dst, degi, rank, nedges);
    k_scan1<<<nodeBlocks, 256, 0, stream>>>(degi, rowptr, bsum);
    k_scan2<<<1, 256, 0, stream>>>(bsum, nodeBlocks);
    k_scan3<<<nodeBlocks, 256, 0, stream>>>(rowptr, bsum, degi, dinv);
    k_fill<<<edgeBlocks, 256, 0, stream>>>(src, dst, rank, rowptr, csr_src, nedges);

    k_fused<<<fusedBlocks, 256, 0, stream>>>(rowptr, csr_src, dinv, TbA,
                                             Wt + 16384, b1, (ushort_t*)TbB);
    k_fused<<<fusedBlocks, 256, 0, stream>>>(rowptr, csr_src, dinv, TbB,
                                             Wt + 32768, b2, (ushort_t*)TbA);
    k_poolgather<<<pgBlocks, 256, 0, stream>>>(rowptr, csr_src, dinv, TbA,
                                               b3, batch, pooled, counts);
    k_cls<<<NUM_GRAPHS, 128, 0, stream>>>(pooled, counts, C1, bc1, C2, bc2,
                                          (float*)d_out);
}

// Round 11
// 276.044 us; speedup vs baseline: 1.4613x; 1.0319x over previous
//
#include <hip/hip_runtime.h>
#include <hip/hip_bf16.h>

#define N_NODES    50000
#define DIM        128
#define NUM_GRAPHS 64
#define NUM_CLASSES 3
#define NPAD       50176   // 196*256
#define XPITCH     136     // LDS row pitch in ushorts (17 x 16B, odd -> conflict-free b128)
#define MMB        782     // (N_NODES+63)/64

typedef unsigned short ushort_t;
typedef unsigned int   uint_t;
typedef __attribute__((ext_vector_type(8))) short short8;
typedef __attribute__((ext_vector_type(4))) float f32x4;

__device__ __forceinline__ ushort_t f2bf(float f) {
    union { float f; uint_t u; } v; v.f = f;
    uint_t r = v.u + 0x7fffu + ((v.u >> 16) & 1u);   // RNE
    return (ushort_t)(r >> 16);
}
__device__ __forceinline__ float bflo(uint_t u) {
    union { uint_t u; float f; } v; v.u = u << 16; return v.f;
}
__device__ __forceinline__ float bfhi(uint_t u) {
    union { uint_t u; float f; } v; v.u = u & 0xffff0000u; return v.f;
}
__device__ __forceinline__ float rlf(float v, int l) {
    union { float f; int i; } c; c.f = v;
    union { int i; float f; } d; d.i = __builtin_amdgcn_readlane(c.i, l);
    return d.f;
}

__device__ __forceinline__ void accum8(float* a, uint4 u) {   // static idx only
    a[0] += bflo(u.x); a[1] += bfhi(u.x);
    a[2] += bflo(u.y); a[3] += bfhi(u.y);
    a[4] += bflo(u.z); a[5] += bfhi(u.z);
    a[6] += bflo(u.w); a[7] += bfhi(u.w);
}
// a[i] += w * row_val[i]
__device__ __forceinline__ void wfma8(float* a, uint4 u, float w) {
    a[0] += w * bflo(u.x); a[1] += w * bfhi(u.x);
    a[2] += w * bflo(u.y); a[3] += w * bfhi(u.y);
    a[4] += w * bflo(u.z); a[5] += w * bfhi(u.z);
    a[6] += w * bflo(u.w); a[7] += w * bfhi(u.w);
}

// pick this quarter-wave's value from 4 wave-uniform scalars (3 cndmask)
__device__ __forceinline__ int qsel(int lane, int s0, int s1, int s2, int s3) {
    int lo = (lane & 16) ? s1 : s0;
    int hi = (lane & 16) ? s3 : s2;
    return (lane & 32) ? hi : lo;
}
__device__ __forceinline__ float qself(int lane, float s0, float s1, float s2, float s3) {
    float lo = (lane & 16) ? s1 : s0;
    float hi = (lane & 16) ? s3 : s2;
    return (lane & 32) ? hi : lo;
}

// -------- round-9 proven UNWEIGHTED quad-lane gather (rows pre-scaled) --------
__device__ __forceinline__ void quad_gather(
    int lane, int m, int myidx0, int p0, int p1,
    const int* __restrict__ csr_src, const uint4* __restrict__ Tb4,
    float* a)
{
    int deg = p1 - p0;
    if (deg < 0) deg = 0;
    int nchunk = (deg + 63) >> 6;
    int myidx = myidx0;
    for (int ck = 0; ck < nchunk; ++ck) {
        int base = p0 + (ck << 6);
        int cnt = p1 - base; if (cnt > 64) cnt = 64;
        int nb = cnt >> 3;                 // 8-edge batches = 2 quad-loads
        if (nb > 0) {
            uint4 u0, u1;
            {
                int s = qsel(lane, __builtin_amdgcn_readlane(myidx, 0),
                                   __builtin_amdgcn_readlane(myidx, 1),
                                   __builtin_amdgcn_readlane(myidx, 2),
                                   __builtin_amdgcn_readlane(myidx, 3));
                u0 = Tb4[s * 16 + m];
                s = qsel(lane, __builtin_amdgcn_readlane(myidx, 4),
                               __builtin_amdgcn_readlane(myidx, 5),
                               __builtin_amdgcn_readlane(myidx, 6),
                               __builtin_amdgcn_readlane(myidx, 7));
                u1 = Tb4[s * 16 + m];
            }
            for (int b = 1; b < nb; ++b) {
                int jb = b * 8;
                uint4 n0, n1;
                int s = qsel(lane, __builtin_amdgcn_readlane(myidx, jb),
                                   __builtin_amdgcn_readlane(myidx, jb + 1),
                                   __builtin_amdgcn_readlane(myidx, jb + 2),
                                   __builtin_amdgcn_readlane(myidx, jb + 3));
                n0 = Tb4[s * 16 + m];
                s = qsel(lane, __builtin_amdgcn_readlane(myidx, jb + 4),
                               __builtin_amdgcn_readlane(myidx, jb + 5),
                               __builtin_amdgcn_readlane(myidx, jb + 6),
                               __builtin_amdgcn_readlane(myidx, jb + 7));
                n1 = Tb4[s * 16 + m];
                accum8(a, u0); accum8(a, u1);
                u0 = n0; u1 = n1;
            }
            accum8(a, u0); accum8(a, u1);
        }
        int j = nb * 8;
        for (; j + 4 <= cnt; j += 4) {     // tail full quads
            int s = qsel(lane, __builtin_amdgcn_readlane(myidx, j),
                               __builtin_amdgcn_readlane(myidx, j + 1),
                               __builtin_amdgcn_readlane(myidx, j + 2),
                               __builtin_amdgcn_readlane(myidx, j + 3));
            uint4 u = Tb4[s * 16 + m];
            accum8(a, u);
        }
        if (j < cnt) {                     // 1..3 tail edges
            int rem = cnt - j;
            int s0 = __builtin_amdgcn_readlane(myidx, j);
            int s1 = __builtin_amdgcn_readlane(myidx, (j + 1 < cnt) ? j + 1 : j);
            int s2 = __builtin_amdgcn_readlane(myidx, (j + 2 < cnt) ? j + 2 : j);
            int s  = qsel(lane, s0, s1, s2, s0);
            if ((lane >> 4) < rem) {
                uint4 u = Tb4[s * 16 + m];
                accum8(a, u);
            }
        }
        if (ck + 1 < nchunk) {             // rare: degree > 64
            int c2 = p1 - (base + 64);
            myidx = (lane < c2) ? csr_src[base + 64 + lane] : 0;
        }
    }
}

// -------- WEIGHTED gather (rows unscaled; w=dinv[src] readlane-fed) ----------
// Used ONLY for layer 1 (enables mm1||count overlap). Layers 2-3 use the
// cheap unweighted core above (round-10 showed the w-tax on all 3 gathers
// eats the overlap win).
__device__ __forceinline__ void quad_gather_w(
    int lane, int m, int myidx0, float myw0, int p0, int p1,
    const int* __restrict__ csr_src, const float* __restrict__ dinv,
    const uint4* __restrict__ Tb4, float* a)
{
    int deg = p1 - p0;
    if (deg < 0) deg = 0;
    int nchunk = (deg + 63) >> 6;
    int myidx = myidx0; float myw = myw0;
    for (int ck = 0; ck < nchunk; ++ck) {
        int base = p0 + (ck << 6);
        int cnt = p1 - base; if (cnt > 64) cnt = 64;
        int nb = cnt >> 3;
        if (nb > 0) {
            uint4 u0, u1; float w0, w1;
            {
                int s = qsel(lane, __builtin_amdgcn_readlane(myidx, 0),
                                   __builtin_amdgcn_readlane(myidx, 1),
                                   __builtin_amdgcn_readlane(myidx, 2),
                                   __builtin_amdgcn_readlane(myidx, 3));
                w0 = qself(lane, rlf(myw, 0), rlf(myw, 1), rlf(myw, 2), rlf(myw, 3));
                u0 = Tb4[s * 16 + m];
                s = qsel(lane, __builtin_amdgcn_readlane(myidx, 4),
                               __builtin_amdgcn_readlane(myidx, 5),
                               __builtin_amdgcn_readlane(myidx, 6),
                               __builtin_amdgcn_readlane(myidx, 7));
                w1 = qself(lane, rlf(myw, 4), rlf(myw, 5), rlf(myw, 6), rlf(myw, 7));
                u1 = Tb4[s * 16 + m];
            }
            for (int b = 1; b < nb; ++b) {
                int jb = b * 8;
                int s = qsel(lane, __builtin_amdgcn_readlane(myidx, jb),
                                   __builtin_amdgcn_readlane(myidx, jb + 1),
                                   __builtin_amdgcn_readlane(myidx, jb + 2),
                                   __builtin_amdgcn_readlane(myidx, jb + 3));
                float nw0 = qself(lane, rlf(myw, jb), rlf(myw, jb + 1),
                                        rlf(myw, jb + 2), rlf(myw, jb + 3));
                uint4 n0v = Tb4[s * 16 + m];
                s = qsel(lane, __builtin_amdgcn_readlane(myidx, jb + 4),
                               __builtin_amdgcn_readlane(myidx, jb + 5),
                               __builtin_amdgcn_readlane(myidx, jb + 6),
                               __builtin_amdgcn_readlane(myidx, jb + 7));
                float nw1 = qself(lane, rlf(myw, jb + 4), rlf(myw, jb + 5),
                                        rlf(myw, jb + 6), rlf(myw, jb + 7));
                uint4 n1v = Tb4[s * 16 + m];
                wfma8(a, u0, w0); wfma8(a, u1, w1);
                u0 = n0v; u1 = n1v; w0 = nw0; w1 = nw1;
            }
            wfma8(a, u0, w0); wfma8(a, u1, w1);
        }
        int j = nb * 8;
        for (; j + 4 <= cnt; j += 4) {
            int s = qsel(lane, __builtin_amdgcn_readlane(myidx, j),
                               __builtin_amdgcn_readlane(myidx, j + 1),
                               __builtin_amdgcn_readlane(myidx, j + 2),
                               __builtin_amdgcn_readlane(myidx, j + 3));
            float w = qself(lane, rlf(myw, j), rlf(myw, j + 1),
                                  rlf(myw, j + 2), rlf(myw, j + 3));
            uint4 u = Tb4[s * 16 + m];
            wfma8(a, u, w);
        }
        if (j < cnt) {
            int rem = cnt - j;
            int j1 = (j + 1 < cnt) ? j + 1 : j;
            int j2 = (j + 2 < cnt) ? j + 2 : j;
            int s = qsel(lane, __builtin_amdgcn_readlane(myidx, j),
                               __builtin_amdgcn_readlane(myidx, j1),
                               __builtin_amdgcn_readlane(myidx, j2),
                               __builtin_amdgcn_readlane(myidx, j));
            float w = qself(lane, rlf(myw, j), rlf(myw, j1), rlf(myw, j2), rlf(myw, j));
            if ((lane >> 4) < rem) {
                uint4 u = Tb4[s * 16 + m];
                wfma8(a, u, w);
            }
        }
        if (ck + 1 < nchunk) {
            int c2 = p1 - (base + 64);
            myidx = (lane < c2) ? csr_src[base + 64 + lane] : 0;
            myw = dinv[myidx];
        }
    }
}

// ---------------- init + W->Wt prep (merged) ----------------
__global__ void k_initprep(int* degi, float* pooled, float* counts,
                           const float* __restrict__ W1, const float* __restrict__ W2,
                           const float* __restrict__ W3, ushort_t* __restrict__ Wt) {
    int i = blockIdx.x * 256 + threadIdx.x;
    if (i < NPAD) degi[i] = 0;
    if (i < NUM_GRAPHS * DIM) pooled[i] = 0.0f;
    if (i < NUM_GRAPHS) counts[i] = 0.0f;
    if (i < 3 * 16384) {
        int mat = i >> 14;
        int idx = i & 16383;
        const float* W = (mat == 0) ? W1 : (mat == 1) ? W2 : W3;
        int n = idx >> 7, k = idx & 127;
        Wt[mat * 16384 + n * 128 + k] = f2bf(W[k * 128 + n]);
    }
}

// ---------------- scan ----------------
__global__ __launch_bounds__(256) void k_scan1(const int* __restrict__ degi,
                                               int* rowptr, int* bsum) {
    __shared__ int sh[256];
    int i = blockIdx.x * 256 + threadIdx.x;
    int v = degi[i];
    sh[threadIdx.x] = v;
    __syncthreads();
    for (int off = 1; off < 256; off <<= 1) {
        int t = (threadIdx.x >= off) ? sh[threadIdx.x - off] : 0;
        __syncthreads();
        sh[threadIdx.x] += t;
        __syncthreads();
    }
    rowptr[i] = sh[threadIdx.x] - v;
    if (threadIdx.x == 255) bsum[blockIdx.x] = sh[255];
}

__global__ __launch_bounds__(256) void k_scan2(int* bsum, int nblocks) {
    __shared__ int sh[256];
    int v = (threadIdx.x < nblocks) ? bsum[threadIdx.x] : 0;
    sh[threadIdx.x] = v;
    __syncthreads();
    for (int off = 1; off < 256; off <<= 1) {
        int t = (threadIdx.x >= off) ? sh[threadIdx.x - off] : 0;
        __syncthreads();
        sh[threadIdx.x] += t;
        __syncthreads();
    }
    if (threadIdx.x < nblocks) bsum[threadIdx.x] = sh[threadIdx.x] - v;
}

// dinv written for ALL of NPAD (padding -> 1.0) so hoisted float4 reads are safe
__global__ __launch_bounds__(256) void k_scan3(int* rowptr, const int* __restrict__ bsum,
                                               const int* __restrict__ degi,
                                               float* dinv) {
    int i = blockIdx.x * 256 + threadIdx.x;
    rowptr[i] = rowptr[i] + bsum[blockIdx.x];
    dinv[i] = rsqrtf((float)degi[i] + 1.0f);
}

// ---------------- CSR fill: atomic-free scatter via precomputed rank ----------------
__global__ void k_fill(const int* __restrict__ src, const int* __restrict__ dst,
                       const int* __restrict__ rank, const int* __restrict__ rowptr,
                       int* csr_src, int nedges) {
    int e = blockIdx.x * 256 + threadIdx.x;
    if (e < nedges) csr_src[rowptr[dst[e]] + rank[e]] = src[e];
}

// ---------------- merged: layer-1 matmul (UNSCALED) + degree count ----------------
__global__ __launch_bounds__(256) void k_mm1c(
    const float* __restrict__ xin, const ushort_t* __restrict__ WtG,
    ushort_t* __restrict__ TbOut,
    const int* __restrict__ dst, int* degi, int* rank, int nedges)
{
    __shared__ ushort_t Wl[DIM * XPITCH];
    __shared__ ushort_t Xl[64 * XPITCH];

    if ((int)blockIdx.x >= MMB) {          // count part (block-uniform branch)
        int e = ((int)blockIdx.x - MMB) * 256 + threadIdx.x;
        if (e < nedges) rank[e] = atomicAdd(&degi[dst[e]], 1);
        return;
    }

    const int tid = threadIdx.x;
    const int rowbase = blockIdx.x * 64;

    #pragma unroll
    for (int i = 0; i < 8; ++i) {
        int g = tid + i * 256;
        uint4 v = ((const uint4*)WtG)[g];
        *((uint4*)&Wl[(g >> 4) * XPITCH + (g & 15) * 8]) = v;
    }
    #pragma unroll
    for (int i = 0; i < 8; ++i) {
        int c = tid + i * 256;
        int row = c >> 5;
        int grow = rowbase + row;
        float4 f = make_float4(0.f, 0.f, 0.f, 0.f);
        if (grow < N_NODES)
            f = ((const float4*)xin)[(long long)rowbase * 32 + c];
        ushort4 h;
        h.x = f2bf(f.x); h.y = f2bf(f.y); h.z = f2bf(f.z); h.w = f2bf(f.w);
        *((ushort4*)&Xl[row * XPITCH + (c & 31) * 4]) = h;
    }
    __syncthreads();

    const int wave = tid >> 6;
    const int lane = tid & 63;
    const int quad = lane >> 4;
    const int lm   = lane & 15;
    const int m0   = wave * 16;

    short8 af[4];
    #pragma unroll
    for (int k0 = 0; k0 < 4; ++k0)
        af[k0] = *(const short8*)&Xl[(m0 + lm) * XPITCH + k0 * 32 + quad * 8];

    int noder[4]; bool okr[4];
    #pragma unroll
    for (int r = 0; r < 4; ++r) {
        noder[r] = rowbase + m0 + quad * 4 + r;
        okr[r] = (noder[r] < N_NODES);
    }

    for (int n0 = 0; n0 < DIM; n0 += 16) {
        f32x4 acc = {0.f, 0.f, 0.f, 0.f};
        #pragma unroll
        for (int k0 = 0; k0 < 4; ++k0) {
            short8 bf = *(const short8*)&Wl[(n0 + lm) * XPITCH + k0 * 32 + quad * 8];
            acc = __builtin_amdgcn_mfma_f32_16x16x32_bf16(af[k0], bf, acc, 0, 0, 0);
        }
        int n = n0 + lm;
        #pragma unroll
        for (int r = 0; r < 4; ++r)
            if (okr[r])
                TbOut[(long long)noder[r] * DIM + n] = f2bf(acc[r]);
    }
}

// ------- layer-1 fused: WEIGHTED gather on unscaled rows; SCALED output -------
__global__ __launch_bounds__(256) void k_fused_w(
    const int* __restrict__ rowptr, const int* __restrict__ csr_src,
    const float* __restrict__ dinv, const uint_t* __restrict__ TbIn,
    const ushort_t* __restrict__ WtG, const float* __restrict__ b_prev,
    ushort_t* __restrict__ TbOut)
{
    __shared__ ushort_t Xl[16 * XPITCH];   // 4352 B

    const int tid = threadIdx.x;
    const int rowbase = blockIdx.x * 16;
    const int wave = tid >> 6;
    const int lane = tid & 63;
    const int m    = lane & 15;
    const uint4* Tb4 = (const uint4*)TbIn;

    float4 blo = ((const float4*)b_prev)[m * 2];
    float4 bhi = ((const float4*)b_prev)[m * 2 + 1];

    const int nfirst = rowbase + wave * 4;
    int pv = (lane < 5) ? rowptr[nfirst + lane] : 0;
    int p[5];
    #pragma unroll
    for (int i = 0; i < 5; ++i) p[i] = __builtin_amdgcn_readlane(pv, i);

    const float4 dv = *(const float4*)&dinv[nfirst];   // NPAD padded -> safe

    int idx_n; float w_n;
    {
        int d0 = p[1] - p[0];
        idx_n = (lane < d0) ? csr_src[p[0] + lane] : 0;
    }
    w_n = dinv[idx_n];

    #pragma unroll
    for (int t = 0; t < 4; ++t) {
        int idx_cur = idx_n; float w_cur = w_n;
        if (t < 3) {
            int dn = p[t + 2] - p[t + 1];
            idx_n = (lane < dn) ? csr_src[p[t + 1] + lane] : 0;
        }
        int r = wave * 4 + t;
        int n = rowbase + r;
        float dd = (t == 0) ? dv.x : (t == 1) ? dv.y : (t == 2) ? dv.z : dv.w;
        float a[8] = {0.f, 0.f, 0.f, 0.f, 0.f, 0.f, 0.f, 0.f};
        uint4 us = make_uint4(0u, 0u, 0u, 0u);
        if (n < N_NODES) {
            us = Tb4[n * 16 + m];
            quad_gather_w(lane, m, idx_cur, w_cur, p[t], p[t + 1],
                          csr_src, dinv, Tb4, a);
        }
        if (t < 3) w_n = dinv[idx_n];
        #pragma unroll
        for (int i = 0; i < 8; ++i) {
            a[i] += __shfl_xor(a[i], 16);
            a[i] += __shfl_xor(a[i], 32);
        }
        wfma8(a, us, dd);                   // self with weight dinv[n]
        if (lane < 16) {
            short8 hh;
            hh[0] = (short)f2bf(fmaxf(blo.x + a[0] * dd, 0.f));
            hh[1] = (short)f2bf(fmaxf(blo.y + a[1] * dd, 0.f));
            hh[2] = (short)f2bf(fmaxf(blo.z + a[2] * dd, 0.f));
            hh[3] = (short)f2bf(fmaxf(blo.w + a[3] * dd, 0.f));
            hh[4] = (short)f2bf(fmaxf(bhi.x + a[4] * dd, 0.f));
            hh[5] = (short)f2bf(fmaxf(bhi.y + a[5] * dd, 0.f));
            hh[6] = (short)f2bf(fmaxf(bhi.z + a[6] * dd, 0.f));
            hh[7] = (short)f2bf(fmaxf(bhi.w + a[7] * dd, 0.f));
            *((short8*)&Xl[r * XPITCH + m * 8]) = hh;
        }
    }
    __syncthreads();

    const int quad = lane >> 4;
    const int lm   = lane & 15;

    short8 af[4];
    #pragma unroll
    for (int k0 = 0; k0 < 4; ++k0)
        af[k0] = *(const short8*)&Xl[lm * XPITCH + k0 * 32 + quad * 8];

    int noder[4]; float di[4]; bool okr[4];
    #pragma unroll
    for (int r = 0; r < 4; ++r) {
        noder[r] = rowbase + quad * 4 + r;
        okr[r] = (noder[r] < N_NODES);
        di[r] = dinv[min(noder[r], NPAD - 1)];
    }

    #pragma unroll
    for (int hh = 0; hh < 2; ++hh) {
        int n0 = wave * 32 + hh * 16;
        f32x4 acc = {0.f, 0.f, 0.f, 0.f};
        #pragma unroll
        for (int k0 = 0; k0 < 4; ++k0) {
            short8 bf = *(const short8*)&WtG[(n0 + lm) * DIM + k0 * 32 + quad * 8];
            acc = __builtin_amdgcn_mfma_f32_16x16x32_bf16(af[k0], bf, acc, 0, 0, 0);
        }
        int n = n0 + lm;
        #pragma unroll
        for (int r = 0; r < 4; ++r)
            if (okr[r])
                TbOut[(long long)noder[r] * DIM + n] = f2bf(acc[r] * di[r]);  // scaled
    }
}

// ------- layers 2: round-9 verbatim (pre-scaled rows, cheap gather) -------
__global__ __launch_bounds__(256) void k_fused(
    const int* __restrict__ rowptr, const int* __restrict__ csr_src,
    const float* __restrict__ dinv, const uint_t* __restrict__ TbIn,
    const ushort_t* __restrict__ WtG, const float* __restrict__ b_prev,
    ushort_t* __restrict__ TbOut)
{
    __shared__ ushort_t Xl[16 * XPITCH];   // 4352 B

    const int tid = threadIdx.x;
    const int rowbase = blockIdx.x * 16;
    const int wave = tid >> 6;
    const int lane = tid & 63;
    const int m    = lane & 15;
    const uint4* Tb4 = (const uint4*)TbIn;

    float4 blo = ((const float4*)b_prev)[m * 2];
    float4 bhi = ((const float4*)b_prev)[m * 2 + 1];

    const int nfirst = rowbase + wave * 4;
    int pv = (lane < 5) ? rowptr[nfirst + lane] : 0;
    int p[5];
    #pragma unroll
    for (int i = 0; i < 5; ++i) p[i] = __builtin_amdgcn_readlane(pv, i);

    int idx_n;
    {
        int d0 = p[1] - p[0];
        idx_n = (lane < d0) ? csr_src[p[0] + lane] : 0;
    }

    #pragma unroll
    for (int t = 0; t < 4; ++t) {
        int idx_cur = idx_n;
        if (t < 3) {
            int dn = p[t + 2] - p[t + 1];
            idx_n = (lane < dn) ? csr_src[p[t + 1] + lane] : 0;
        }
        int r = wave * 4 + t;
        int n = rowbase + r;
        float a[8] = {0.f, 0.f, 0.f, 0.f, 0.f, 0.f, 0.f, 0.f};
        float dd = 0.f;
        uint4 us = make_uint4(0u, 0u, 0u, 0u);
        if (n < N_NODES) {
            us = Tb4[n * 16 + m];
            dd = dinv[n];
            quad_gather(lane, m, idx_cur, p[t], p[t + 1], csr_src, Tb4, a);
        }
        #pragma unroll
        for (int i = 0; i < 8; ++i) {
            a[i] += __shfl_xor(a[i], 16);
            a[i] += __shfl_xor(a[i], 32);
        }
        accum8(a, us);
        if (lane < 16) {
            short8 hh;
            hh[0] = (short)f2bf(fmaxf(blo.x + a[0] * dd, 0.f));
            hh[1] = (short)f2bf(fmaxf(blo.y + a[1] * dd, 0.f));
            hh[2] = (short)f2bf(fmaxf(blo.z + a[2] * dd, 0.f));
            hh[3] = (short)f2bf(fmaxf(blo.w + a[3] * dd, 0.f));
            hh[4] = (short)f2bf(fmaxf(bhi.x + a[4] * dd, 0.f));
            hh[5] = (short)f2bf(fmaxf(bhi.y + a[5] * dd, 0.f));
            hh[6] = (short)f2bf(fmaxf(bhi.z + a[6] * dd, 0.f));
            hh[7] = (short)f2bf(fmaxf(bhi.w + a[7] * dd, 0.f));
            *((short8*)&Xl[r * XPITCH + m * 8]) = hh;
        }
    }
    __syncthreads();

    const int quad = lane >> 4;
    const int lm   = lane & 15;

    short8 af[4];
    #pragma unroll
    for (int k0 = 0; k0 < 4; ++k0)
        af[k0] = *(const short8*)&Xl[lm * XPITCH + k0 * 32 + quad * 8];

    int noder[4]; float di[4]; bool okr[4];
    #pragma unroll
    for (int r = 0; r < 4; ++r) {
        noder[r] = rowbase + quad * 4 + r;
        okr[r] = (noder[r] < N_NODES);
        di[r] = dinv[min(noder[r], NPAD - 1)];
    }

    #pragma unroll
    for (int hh = 0; hh < 2; ++hh) {
        int n0 = wave * 32 + hh * 16;
        f32x4 acc = {0.f, 0.f, 0.f, 0.f};
        #pragma unroll
        for (int k0 = 0; k0 < 4; ++k0) {
            short8 bf = *(const short8*)&WtG[(n0 + lm) * DIM + k0 * 32 + quad * 8];
            acc = __builtin_amdgcn_mfma_f32_16x16x32_bf16(af[k0], bf, acc, 0, 0, 0);
        }
        int n = n0 + lm;
        #pragma unroll
        for (int r = 0; r < 4; ++r)
            if (okr[r])
                TbOut[(long long)noder[r] * DIM + n] = f2bf(acc[r] * di[r]);
    }
}

// ------- pool: round-9 verbatim (pre-scaled rows, cheap gather) -------
__global__ __launch_bounds__(256) void k_poolgather(
    const int* __restrict__ rowptr, const int* __restrict__ csr_src,
    const float* __restrict__ dinv, const uint_t* __restrict__ Tb,
    const float* __restrict__ b3, const int* __restrict__ batch,
    float* pooled, float* counts)
{
    __shared__ float lp[8][DIM];   // 4 KB
    __shared__ float lc[8];

    const int tid  = threadIdx.x;
    const int wave = tid >> 6;
    const int lane = tid & 63;
    const int m    = lane & 15;
    const int q    = lane >> 4;
    const int blk0 = blockIdx.x * 32;
    const uint4* Tb4 = (const uint4*)Tb;
    const int ch = 8 * m + 2 * q;

    #pragma unroll
    for (int i = 0; i < 4; ++i) ((float*)lp)[tid + i * 256] = 0.f;
    if (tid < 8) lc[tid] = 0.f;
    __syncthreads();

    const int gbase = batch[min(blk0, N_NODES - 1)];
    int n0 = blk0 + wave * 8;

    if (n0 < N_NODES) {
        int nend = min(n0 + 8, N_NODES);
        float bb0 = b3[ch], bb1 = b3[ch + 1];

        int pv = (lane < 9) ? rowptr[min(n0 + lane, NPAD)] : 0;
        int p[9];
        #pragma unroll
        for (int i = 0; i < 9; ++i) p[i] = __builtin_amdgcn_readlane(pv, i);

        int cur = batch[n0];
        int runstart = n0;
        float2 pacc = make_float2(0.f, 0.f);

        int idx_n;
        {
            int d0 = p[1] - p[0];
            idx_n = (lane < d0) ? csr_src[p[0] + lane] : 0;
        }

        for (int i = 0; i < nend - n0; ++i) {
            int n = n0 + i;
            int idx_cur = idx_n;
            if (i < 7) {
                int dn = p[i + 2] - p[i + 1];
                idx_n = (lane < dn) ? csr_src[p[i + 1] + lane] : 0;
            }
            int g = batch[n];
            if (g != cur) {
                int slot = cur - gbase;
                if (slot < 8) {
                    atomicAdd(&lp[slot][ch], pacc.x);
                    atomicAdd(&lp[slot][ch + 1], pacc.y);
                    if (lane == 0) atomicAdd(&lc[slot], (float)(n - runstart));
                } else {
                    atomicAdd(&pooled[cur * DIM + ch], pacc.x);
                    atomicAdd(&pooled[cur * DIM + ch + 1], pacc.y);
                    if (lane == 0) atomicAdd(&counts[cur], (float)(n - runstart));
                }
                pacc.x = 0.f; pacc.y = 0.f; cur = g; runstart = n;
            }
            float a[8] = {0.f, 0.f, 0.f, 0.f, 0.f, 0.f, 0.f, 0.f};
            uint4 us = Tb4[n * 16 + m];
            quad_gather(lane, m, idx_cur, p[i], p[i + 1], csr_src, Tb4, a);
            #pragma unroll
            for (int k = 0; k < 8; ++k) {
                a[k] += __shfl_xor(a[k], 16);
                a[k] += __shfl_xor(a[k], 32);
            }
            accum8(a, us);
            float x0 = (q == 0) ? a[0] : (q == 1) ? a[2] : (q == 2) ? a[4] : a[6];
            float x1 = (q == 0) ? a[1] : (q == 1) ? a[3] : (q == 2) ? a[5] : a[7];
            float dd = dinv[n];
            pacc.x += bb0 + x0 * dd;
            pacc.y += bb1 + x1 * dd;
        }
        int slot = cur - gbase;
        if (slot < 8) {
            atomicAdd(&lp[slot][ch], pacc.x);
            atomicAdd(&lp[slot][ch + 1], pacc.y);
            if (lane == 0) atomicAdd(&lc[slot], (float)(nend - runstart));
        } else {
            atomicAdd(&pooled[cur * DIM + ch], pacc.x);
            atomicAdd(&pooled[cur * DIM + ch + 1], pacc.y);
            if (lane == 0) atomicAdd(&counts[cur], (float)(nend - runstart));
        }
    }
    __syncthreads();

    #pragma unroll
    for (int s = 0; s < 8; ++s) {
        if (lc[s] != 0.f) {
            if (tid < DIM) atomicAdd(&pooled[(gbase + s) * DIM + tid], lp[s][tid]);
            if (tid == DIM) atomicAdd(&counts[gbase + s], lc[s]);
        }
    }
}

// ---------------- classifier head ----------------
__global__ __launch_bounds__(128) void k_cls(
    const float* __restrict__ pooled, const float* __restrict__ counts,
    const float* __restrict__ C1, const float* __restrict__ bc1,
    const float* __restrict__ C2, const float* __restrict__ bc2,
    float* out)
{
    __shared__ float pm[DIM];
    __shared__ float gv[DIM];
    int g = blockIdx.x, j = threadIdx.x;
    float cnt = fmaxf(counts[g], 1.0f);
    pm[j] = pooled[g * DIM + j] / cnt;
    __syncthreads();
    float a = bc1[j];
    for (int k = 0; k < DIM; ++k) a += pm[k] * C1[k * DIM + j];
    gv[j] = fmaxf(a, 0.f);
    __syncthreads();
    if (j < NUM_CLASSES) {
        float o = bc2[j];
        for (int k = 0; k < DIM; ++k) o += gv[k] * C2[k * NUM_CLASSES + j];
        out[g * NUM_CLASSES + j] = o;
    }
}

extern "C" void kernel_launch(void* const* d_in, const int* in_sizes, int n_in,
                              void* d_out, int out_size, void* d_ws, size_t ws_size,
                              hipStream_t stream) {
    const float* x    = (const float*)d_in[0];
    const int*   ei   = (const int*)d_in[1];
    const int*   batch= (const int*)d_in[2];
    const float* W1   = (const float*)d_in[3];
    const float* b1   = (const float*)d_in[4];
    const float* W2   = (const float*)d_in[5];
    const float* b2   = (const float*)d_in[6];
    const float* W3   = (const float*)d_in[7];
    const float* b3   = (const float*)d_in[8];
    const float* C1   = (const float*)d_in[9];
    const float* bc1  = (const float*)d_in[10];
    const float* C2   = (const float*)d_in[11];
    const float* bc2  = (const float*)d_in[12];

    const int nedges = in_sizes[1] / 2;
    const int* src = ei;
    const int* dst = ei + nedges;

    // workspace layout (4-byte units)
    float*    dinv    = (float*)d_ws;                           // NPAD
    uint_t*   TbA     = (uint_t*)(dinv + NPAD);                 // N_NODES*64
    uint_t*   TbB     = TbA + (long long)N_NODES * 64;          // N_NODES*64
    float*    pooled  = (float*)(TbB + (long long)N_NODES * 64);// 8192
    float*    counts  = pooled + NUM_GRAPHS * DIM;              // 64
    int*      degi    = (int*)(counts + 64);                    // NPAD
    int*      rowptr  = degi + NPAD;                            // NPAD+256
    int*      bsum    = rowptr + NPAD + 256;                    // 256
    int*      rank    = bsum + 256;                             // nedges
    int*      csr_src = rank + nedges;                          // nedges
    ushort_t* Wt      = (ushort_t*)(csr_src + nedges);          // 3*16384 bf16

    const int nodeBlocks = NPAD / 256;                     // 196
    const int fusedBlocks= (N_NODES + 15) / 16;            // 3125
    const int pgBlocks   = (N_NODES + 31) / 32;            // 1563
    const int edgeBlocks = (nedges + 255) / 256;           // 3125

    k_initprep<<<nodeBlocks, 256, 0, stream>>>(degi, pooled, counts, W1, W2, W3, Wt);
    k_mm1c<<<MMB + edgeBlocks, 256, 0, stream>>>(x, Wt, (ushort_t*)TbA,
                                                 dst, degi, rank, nedges);
    k_scan1<<<nodeBlocks, 256, 0, stream>>>(degi, rowptr, bsum);
    k_scan2<<<1, 256, 0, stream>>>(bsum, nodeBlocks);
    k_scan3<<<nodeBlocks, 256, 0, stream>>>(rowptr, bsum, degi, dinv);
    k_fill<<<edgeBlocks, 256, 0, stream>>>(src, dst, rank, rowptr, csr_src, nedges);

    k_fused_w<<<fusedBlocks, 256, 0, stream>>>(rowptr, csr_src, dinv, TbA,
                                               Wt + 16384, b1, (ushort_t*)TbB);
    k_fused<<<fusedBlocks, 256, 0, stream>>>(rowptr, csr_src, dinv, TbB,
                                             Wt + 32768, b2, (ushort_t*)TbA);
    k_poolgather<<<pgBlocks, 256, 0, stream>>>(rowptr, csr_src, dinv, TbA,
                                               b3, batch, pooled, counts);
    k_cls<<<NUM_GRAPHS, 128, 0, stream>>>(pooled, counts, C1, bc1, C2, bc2,
                                          (float*)d_out);
}